// Round 5
// baseline (576.505 us; speedup 1.0000x reference)
//
#include <hip/hip_runtime.h>
#include <hip/hip_bf16.h>

typedef __attribute__((ext_vector_type(8))) short bf16x8;
typedef __attribute__((ext_vector_type(4))) short bf16x4;
typedef __attribute__((ext_vector_type(4))) float f32x4;

#define MFMA16(a, b, c) __builtin_amdgcn_mfma_f32_16x16x32_bf16((a), (b), (c), 0, 0, 0)

__device__ __forceinline__ f32x4 mfma_k16(bf16x4 a, bf16x4 b, f32x4 c) {
#if __has_builtin(__builtin_amdgcn_mfma_f32_16x16x16bf16_1k)
  return __builtin_amdgcn_mfma_f32_16x16x16bf16_1k(a, b, c, 0, 0, 0);
#elif __has_builtin(__builtin_amdgcn_mfma_f32_16x16x16_bf16)
  return __builtin_amdgcn_mfma_f32_16x16x16_bf16(a, b, c, 0, 0, 0);
#else
  asm("v_mfma_f32_16x16x16_bf16 %0, %1, %2, %0" : "+v"(c) : "v"(a), "v"(b));
  return c;
#endif
}

__device__ __forceinline__ ushort f2bf(float f) {
  union { __hip_bfloat16 h; ushort u; } cv;
  cv.h = __float2bfloat16(f);
  return cv.u;
}

__device__ __forceinline__ void gload16(const void* g, void* l) {
  __builtin_amdgcn_global_load_lds((const __attribute__((address_space(1))) void*)g,
                                   (__attribute__((address_space(3))) void*)l, 16, 0, 0);
}

// ---------------- fp32 (K x N) -> bf16 transposed (N x K) ----------------
__global__ void wtrans_kernel(const float* __restrict__ W, ushort* __restrict__ Wt,
                              int K, int N) {
  __shared__ float t[32][33];
  const int tx = threadIdx.x & 31, ty = threadIdx.x >> 5;
  const int nb = blockIdx.x * 32, kb = blockIdx.y * 32;
#pragma unroll
  for (int i = 0; i < 4; ++i)
    t[ty + i * 8][tx] = W[(size_t)(kb + ty + i * 8) * N + nb + tx];
  __syncthreads();
#pragma unroll
  for (int i = 0; i < 4; ++i)
    Wt[(size_t)(nb + ty + i * 8) * K + kb + tx] = f2bf(t[tx][ty + i * 8]);
}

// ---------------- RMSNorm fp32 row(768) -> bf16 ----------------
__global__ void rmsnorm_kernel(const float* __restrict__ x, const float* __restrict__ g,
                               ushort* __restrict__ out) {
  const int row = blockIdx.x;
  const float* xr = x + (size_t)row * 768;
  const int t = threadIdx.x;
  float v0 = xr[t], v1 = xr[t + 256], v2 = xr[t + 512];
  float ss = v0 * v0 + v1 * v1 + v2 * v2;
#pragma unroll
  for (int off = 1; off < 64; off <<= 1) ss += __shfl_xor(ss, off);
  __shared__ float part[4];
  if ((t & 63) == 0) part[t >> 6] = ss;
  __syncthreads();
  const float tot = part[0] + part[1] + part[2] + part[3];
  const float r = rsqrtf(tot * (1.0f / 768.0f) + 1e-6f);
  ushort* orow = out + (size_t)row * 768;
  orow[t]       = f2bf(v0 * r * g[t]);
  orow[t + 256] = f2bf(v1 * r * g[t + 256]);
  orow[t + 512] = f2bf(v2 * r * g[t + 512]);
}

// ---------------- GEMM: C(MxN) = A(MxK,bf16) * Bt(NxK,bf16)^T ----------------
enum { EPI_BF16 = 0, EPI_VT = 1, EPI_RESID = 2, EPI_BIAS_GELU = 3, EPI_BIAS_RESID = 4 };

template <int EPI>
__global__ __launch_bounds__(256) void gemm_bt(
    const ushort* __restrict__ A, const ushort* __restrict__ Bt, void* __restrict__ Cout,
    const float* __restrict__ bias, const float* __restrict__ resid, int M, int N, int K,
    float scale) {
  __shared__ ushort As[128 * 64];
  __shared__ ushort Bs[128 * 64];
  const int tid = threadIdx.x;
  const int lane = tid & 63, wid = tid >> 6;
  const int wm = wid >> 1, wn = wid & 1;
  const int l15 = lane & 15, l4 = lane >> 4;
  const int m0 = blockIdx.y * 128, n0 = blockIdx.x * 128;
  const int srow = lane >> 3, sslot = lane & 7;
  const int skel = (sslot ^ srow) << 3;

  f32x4 acc[4][4] = {};

  for (int k0 = 0; k0 < K; k0 += 64) {
    __syncthreads();
#pragma unroll
    for (int i = 0; i < 4; ++i) {
      const int c = i * 4 + wid;
      const int row = c * 8 + srow;
      gload16(A + (size_t)(m0 + row) * K + k0 + skel, (char*)As + c * 1024);
      gload16(Bt + (size_t)(n0 + row) * K + k0 + skel, (char*)Bs + c * 1024);
    }
    __syncthreads();
#pragma unroll
    for (int ks = 0; ks < 2; ++ks) {
      bf16x8 af[4], bfr[4];
#pragma unroll
      for (int mi = 0; mi < 4; ++mi) {
        const int row = wm * 64 + mi * 16 + l15;
        const int slot = (ks * 4 + l4) ^ (row & 7);
        af[mi] = *(const bf16x8*)((const char*)As + row * 128 + slot * 16);
      }
#pragma unroll
      for (int ni = 0; ni < 4; ++ni) {
        const int row = wn * 64 + ni * 16 + l15;
        const int slot = (ks * 4 + l4) ^ (row & 7);
        bfr[ni] = *(const bf16x8*)((const char*)Bs + row * 128 + slot * 16);
      }
#pragma unroll
      for (int mi = 0; mi < 4; ++mi)
#pragma unroll
        for (int ni = 0; ni < 4; ++ni)
          acc[mi][ni] = MFMA16(af[mi], bfr[ni], acc[mi][ni]);
    }
  }

#pragma unroll
  for (int mi = 0; mi < 4; ++mi) {
#pragma unroll
    for (int ni = 0; ni < 4; ++ni) {
      const int gm = m0 + wm * 64 + mi * 16 + l4 * 4;
      const int gn = n0 + wn * 64 + ni * 16 + l15;
      f32x4 v = acc[mi][ni];
#pragma unroll
      for (int r = 0; r < 4; ++r) {
        const size_t idx = (size_t)(gm + r) * N + gn;
        const float f = v[r];
        if constexpr (EPI == EPI_BF16) {
          ((ushort*)Cout)[idx] = f2bf(f * scale);
        } else if constexpr (EPI == EPI_RESID) {
          ((float*)Cout)[idx] = f + resid[idx];
        } else if constexpr (EPI == EPI_BIAS_GELU) {
          const float u = f + bias[gn];
          const float gl = 0.5f * u * (1.0f + erff(u * 0.70710678118654752f));
          ((ushort*)Cout)[idx] = f2bf(gl);
        } else if constexpr (EPI == EPI_BIAS_RESID) {
          ((float*)Cout)[idx] = f + bias[gn] + resid[idx];
        }
      }
    }
  }
}

// ---------------- merged QKV GEMM: N=2304, segment epilogue ----------------
__global__ __launch_bounds__(256) void gemm_qkv(
    const ushort* __restrict__ A, const ushort* __restrict__ Bt,
    ushort* __restrict__ qout, ushort* __restrict__ kout, ushort* __restrict__ vtout,
    int M, int K, float qscale) {
  __shared__ ushort As[128 * 64];
  __shared__ ushort Bs[128 * 64];
  const int tid = threadIdx.x;
  const int lane = tid & 63, wid = tid >> 6;
  const int wm = wid >> 1, wn = wid & 1;
  const int l15 = lane & 15, l4 = lane >> 4;
  const int m0 = blockIdx.y * 128, n0 = blockIdx.x * 128;
  const int srow = lane >> 3, sslot = lane & 7;
  const int skel = (sslot ^ srow) << 3;

  f32x4 acc[4][4] = {};

  for (int k0 = 0; k0 < K; k0 += 64) {
    __syncthreads();
#pragma unroll
    for (int i = 0; i < 4; ++i) {
      const int c = i * 4 + wid;
      const int row = c * 8 + srow;
      gload16(A + (size_t)(m0 + row) * K + k0 + skel, (char*)As + c * 1024);
      gload16(Bt + (size_t)(n0 + row) * K + k0 + skel, (char*)Bs + c * 1024);
    }
    __syncthreads();
#pragma unroll
    for (int ks = 0; ks < 2; ++ks) {
      bf16x8 af[4], bfr[4];
#pragma unroll
      for (int mi = 0; mi < 4; ++mi) {
        const int row = wm * 64 + mi * 16 + l15;
        const int slot = (ks * 4 + l4) ^ (row & 7);
        af[mi] = *(const bf16x8*)((const char*)As + row * 128 + slot * 16);
      }
#pragma unroll
      for (int ni = 0; ni < 4; ++ni) {
        const int row = wn * 64 + ni * 16 + l15;
        const int slot = (ks * 4 + l4) ^ (row & 7);
        bfr[ni] = *(const bf16x8*)((const char*)Bs + row * 128 + slot * 16);
      }
#pragma unroll
      for (int mi = 0; mi < 4; ++mi)
#pragma unroll
        for (int ni = 0; ni < 4; ++ni)
          acc[mi][ni] = MFMA16(af[mi], bfr[ni], acc[mi][ni]);
    }
  }

  const int seg = n0 / 768;  // uniform per block (768 % 128 == 0)
#pragma unroll
  for (int mi = 0; mi < 4; ++mi) {
#pragma unroll
    for (int ni = 0; ni < 4; ++ni) {
      const int gm = m0 + wm * 64 + mi * 16 + l4 * 4;
      const int gn = n0 + wn * 64 + ni * 16 + l15;
      const int col = gn - seg * 768;
      f32x4 v = acc[mi][ni];
      if (seg == 0) {
#pragma unroll
        for (int r = 0; r < 4; ++r)
          qout[(size_t)(gm + r) * 768 + col] = f2bf(v[r] * qscale);
      } else if (seg == 1) {
#pragma unroll
        for (int r = 0; r < 4; ++r)
          kout[(size_t)(gm + r) * 768 + col] = f2bf(v[r]);
      } else {
        const int b = gm >> 12, tt = gm & 4095;
        const int h = col >> 6, dh = col & 63;
        ushort4 pk;
        pk.x = f2bf(v[0]); pk.y = f2bf(v[1]); pk.z = f2bf(v[2]); pk.w = f2bf(v[3]);
        *(ushort4*)(vtout + (((size_t)(b * 12 + h) * 64 + dh) * 4096 + tt)) = pk;
      }
    }
  }
}

// ---------------- causal MFMA flash attention (32 q-rows/wave) ----------------
// Q,K row-major [B*T][768] bf16 (Q pre-scaled by 0.125/ln2); Vt [B][H][64][T].
// Swapped QK^T; each wave owns 2 16-row Q sub-tiles -> every K/V LDS fragment
// feeds 2 MFMAs. Static max, deferred denominator.
__global__ __launch_bounds__(256) void flash_attn_kernel(
    const ushort* __restrict__ Q, const ushort* __restrict__ Kb,
    const ushort* __restrict__ Vt, ushort* __restrict__ O) {
  __shared__ ushort Ks[2][128 * 64];    // [key][kd], 8-slot XOR swizzle
  __shared__ ushort Vts[2][64 * 128];   // [dh][key], 16-slot XOR swizzle
  const int tid = threadIdx.x, lane = tid & 63, wid = tid >> 6;
  const int l15 = lane & 15, l4 = lane >> 4;
  const int bh = blockIdx.y, b = bh / 12, h = bh % 12;
  const int qc = 31 - (int)blockIdx.x;  // heavy blocks dispatched first
  const int qbase = qc * 128;
  const int q0 = qbase + wid * 32;      // wave's 32 q-rows

  bf16x8 qf00, qf01, qf10, qf11;
  {
    const ushort* qp0 = Q + ((size_t)(b * 4096 + q0 + l15) * 768 + h * 64 + l4 * 8);
    qf00 = *(const bf16x8*)qp0;
    qf01 = *(const bf16x8*)(qp0 + 32);
    const ushort* qp1 = qp0 + (size_t)16 * 768;
    qf10 = *(const bf16x8*)qp1;
    qf11 = *(const bf16x8*)(qp1 + 32);
  }
  f32x4 oo0[4] = {}, oo1[4] = {};
  float dsum0 = 0.f, dsum1 = 0.f;

  const int krow_l = lane >> 3;
  const int kco = ((lane & 7) ^ krow_l) << 3;
  const int vrow_l = lane >> 4;
  const ushort* Kbase = Kb + (size_t)b * 4096 * 768 + h * 64;
  const ushort* Vbase = Vt + (size_t)bh * 64 * 4096;
  const int nt = qc + 1;

  // ---- prologue: stage tile 0 into buffer 0 ----
#pragma unroll
  for (int i = 0; i < 4; ++i) {
    const int krow = wid * 32 + i * 8 + krow_l;
    gload16(Kbase + (size_t)krow * 768 + kco, (char*)Ks[0] + (wid * 32 + i * 8) * 128);
    const int vrow = wid * 16 + i * 4 + vrow_l;
    const int vsw = ((lane & 15) ^ (vrow & 15)) << 3;
    gload16(Vbase + (size_t)vrow * 4096 + vsw, (char*)Vts[0] + (wid * 16 + i * 4) * 256);
  }

  int cur = 0;
  for (int kt = 0; kt < nt; ++kt) {
    const int k0 = kt << 7;
    if (kt + 1 < nt) {
      const int kn = (kt + 1) << 7;
#pragma unroll
      for (int i = 0; i < 4; ++i) {
        const int krow = wid * 32 + i * 8 + krow_l;
        gload16(Kbase + (size_t)(kn + krow) * 768 + kco,
                (char*)Ks[cur ^ 1] + (wid * 32 + i * 8) * 128);
        const int vrow = wid * 16 + i * 4 + vrow_l;
        const int vsw = ((lane & 15) ^ (vrow & 15)) << 3;
        gload16(Vbase + (size_t)vrow * 4096 + kn + vsw,
                (char*)Vts[cur ^ 1] + (wid * 16 + i * 4) * 256);
      }
      asm volatile("s_waitcnt vmcnt(8)" ::: "memory");
    } else {
      asm volatile("s_waitcnt vmcnt(0)" ::: "memory");
    }
    __builtin_amdgcn_s_barrier();

    const int nf0 = (q0 + 16 - k0) >> 4;  // >= 1 always
    const int nct0 = nf0 < 8 ? nf0 : 8;
    const int nf1 = nf0 + 1;
    const int nct1 = nf1 < 8 ? nf1 : 8;
    const bool hd0 = (nf0 <= 8), hd1 = (nf1 <= 8);
    const ushort* Kc = Ks[cur];
    const ushort* Vc = Vts[cur];

#pragma unroll
    for (int ct = 0; ct < 8; ++ct) {
      if (ct < nct1) {
        const int key = ct * 16 + l15;
        const int slot0 = l4 ^ (key & 7);
        const bf16x8 kf0 = *(const bf16x8*)((const char*)Kc + key * 128 + slot0 * 16);
        const int slot1 = (4 + l4) ^ (key & 7);
        const bf16x8 kf1 = *(const bf16x8*)((const char*)Kc + key * 128 + slot1 * 16);
        const bool a0 = (ct < nct0);

        f32x4 s1v = {0.f, 0.f, 0.f, 0.f};
        s1v = MFMA16(kf0, qf10, s1v);
        s1v = MFMA16(kf1, qf11, s1v);
        f32x4 s0v = {0.f, 0.f, 0.f, 0.f};
        if (a0) {
          s0v = MFMA16(kf0, qf00, s0v);
          s0v = MFMA16(kf1, qf01, s0v);
        }
        if (a0 && hd0 && ct == nct0 - 1) {
#pragma unroll
          for (int r = 0; r < 4; ++r)
            if (l4 * 4 + r > l15) s0v[r] = -30.f;
        }
        if (hd1 && ct == nct1 - 1) {
#pragma unroll
          for (int r = 0; r < 4; ++r)
            if (l4 * 4 + r > l15) s1v[r] = -30.f;
        }

        union { bf16x4 v; ushort u[4]; } pk0, pk1;
        {
          const float p0 = __builtin_amdgcn_exp2f(s1v[0]);
          const float p1 = __builtin_amdgcn_exp2f(s1v[1]);
          const float p2 = __builtin_amdgcn_exp2f(s1v[2]);
          const float p3 = __builtin_amdgcn_exp2f(s1v[3]);
          dsum1 += (p0 + p1) + (p2 + p3);
          pk1.u[0] = f2bf(p0); pk1.u[1] = f2bf(p1);
          pk1.u[2] = f2bf(p2); pk1.u[3] = f2bf(p3);
        }
        if (a0) {
          const float p0 = __builtin_amdgcn_exp2f(s0v[0]);
          const float p1 = __builtin_amdgcn_exp2f(s0v[1]);
          const float p2 = __builtin_amdgcn_exp2f(s0v[2]);
          const float p3 = __builtin_amdgcn_exp2f(s0v[3]);
          dsum0 += (p0 + p1) + (p2 + p3);
          pk0.u[0] = f2bf(p0); pk0.u[1] = f2bf(p1);
          pk0.u[2] = f2bf(p2); pk0.u[3] = f2bf(p3);
        }

        const int t2 = 2 * ct + (l4 >> 1);
        const int half = (l4 & 1) << 2;
#pragma unroll
        for (int dt = 0; dt < 4; ++dt) {
          const int dh = dt * 16 + l15;
          const int off = dh * 128 + ((t2 ^ (dh & 15)) << 3) + half;
          const bf16x4 vf = *(const bf16x4*)(Vc + off);
          oo1[dt] = mfma_k16(pk1.v, vf, oo1[dt]);
          if (a0) oo0[dt] = mfma_k16(pk0.v, vf, oo0[dt]);
        }
      }
    }
    asm volatile("" ::: "memory");
    __builtin_amdgcn_s_barrier();
    cur ^= 1;
  }

  // ---- final denominator reduce + normalize + store ----
  dsum0 += __shfl_xor(dsum0, 16);
  dsum0 += __shfl_xor(dsum0, 32);
  dsum1 += __shfl_xor(dsum1, 16);
  dsum1 += __shfl_xor(dsum1, 32);
  {
    ushort* op = O + ((size_t)(b * 4096 + q0 + l4 * 4) * 768 + h * 64);
#pragma unroll
    for (int r = 0; r < 4; ++r) {
      const float inv = 1.0f / __shfl(dsum0, l4 * 4 + r);
#pragma unroll
      for (int dt = 0; dt < 4; ++dt)
        op[(size_t)r * 768 + dt * 16 + l15] = f2bf(oo0[dt][r] * inv);
    }
  }
  {
    ushort* op = O + ((size_t)(b * 4096 + q0 + 16 + l4 * 4) * 768 + h * 64);
#pragma unroll
    for (int r = 0; r < 4; ++r) {
      const float inv = 1.0f / __shfl(dsum1, l4 * 4 + r);
#pragma unroll
      for (int dt = 0; dt < 4; ++dt)
        op[(size_t)r * 768 + dt * 16 + l15] = f2bf(oo1[dt][r] * inv);
    }
  }
}

extern "C" void kernel_launch(void* const* d_in, const int* in_sizes, int n_in,
                              void* d_out, int out_size, void* d_ws, size_t ws_size,
                              hipStream_t stream) {
  const float* x  = (const float*)d_in[0];
  const float* wq = (const float*)d_in[1];
  const float* wk = (const float*)d_in[2];
  const float* wv = (const float*)d_in[3];
  const float* wo = (const float*)d_in[4];
  const float* w1 = (const float*)d_in[5];
  const float* b1 = (const float*)d_in[6];
  const float* w2 = (const float*)d_in[7];
  const float* b2 = (const float*)d_in[8];
  const float* g1 = (const float*)d_in[9];
  const float* g2 = (const float*)d_in[10];
  float* out = (float*)d_out;

  char* p = (char*)d_ws;
  ushort* wqT = (ushort*)p; p += (size_t)768 * 768 * 2;   // } contiguous: acts as
  ushort* wkT = (ushort*)p; p += (size_t)768 * 768 * 2;   // } one 2304x768 B matrix
  ushort* wvT = (ushort*)p; p += (size_t)768 * 768 * 2;   // } for merged QKV GEMM
  ushort* woT = (ushort*)p; p += (size_t)768 * 768 * 2;
  ushort* w1T = (ushort*)p; p += (size_t)3072 * 768 * 2;
  ushort* w2T = (ushort*)p; p += (size_t)768 * 3072 * 2;
  ushort* xn  = (ushort*)p; p += (size_t)8192 * 768 * 2;
  ushort* qb  = (ushort*)p; p += (size_t)8192 * 768 * 2;
  ushort* kb  = (ushort*)p; p += (size_t)8192 * 768 * 2;
  ushort* vtb = (ushort*)p; p += (size_t)8192 * 768 * 2;
  ushort* attn = (ushort*)p; p += (size_t)8192 * 768 * 2;
  float* x2 = (float*)p; p += (size_t)8192 * 768 * 4;
  ushort* hf = qb;  // reuse qb..attn region (exactly 8192*3072*2 bytes)

  // Q pre-scale folds 1/sqrt(64) and 1/ln2 (softmax computed in exp2 units)
  const float qscale = 0.125f * 1.44269504088896340736f;

  dim3 blk(256);
  wtrans_kernel<<<dim3(24, 24), blk, 0, stream>>>(wq, wqT, 768, 768);
  wtrans_kernel<<<dim3(24, 24), blk, 0, stream>>>(wk, wkT, 768, 768);
  wtrans_kernel<<<dim3(24, 24), blk, 0, stream>>>(wv, wvT, 768, 768);
  wtrans_kernel<<<dim3(24, 24), blk, 0, stream>>>(wo, woT, 768, 768);
  wtrans_kernel<<<dim3(96, 24), blk, 0, stream>>>(w1, w1T, 768, 3072);
  wtrans_kernel<<<dim3(24, 96), blk, 0, stream>>>(w2, w2T, 3072, 768);

  rmsnorm_kernel<<<8192, blk, 0, stream>>>(x, g1, xn);

  gemm_qkv<<<dim3(18, 64), blk, 0, stream>>>(xn, wqT, qb, kb, vtb, 8192, 768, qscale);

  flash_attn_kernel<<<dim3(32, 24), blk, 0, stream>>>(qb, kb, vtb, attn);

  gemm_bt<EPI_RESID><<<dim3(6, 64), blk, 0, stream>>>(attn, woT, x2, nullptr, x, 8192, 768, 768, 1.0f);

  rmsnorm_kernel<<<8192, blk, 0, stream>>>(x2, g2, xn);

  gemm_bt<EPI_BIAS_GELU><<<dim3(24, 64), blk, 0, stream>>>(xn, w1T, hf, b1, nullptr, 8192, 3072, 768, 1.0f);
  gemm_bt<EPI_BIAS_RESID><<<dim3(6, 64), blk, 0, stream>>>(hf, w2T, out, b2, x2, 8192, 768, 3072, 1.0f);
}

// Round 6
// 411.850 us; speedup vs baseline: 1.3998x; 1.3998x over previous
//
#include <hip/hip_runtime.h>
#include <hip/hip_bf16.h>

typedef __attribute__((ext_vector_type(8))) short bf16x8;
typedef __attribute__((ext_vector_type(4))) short bf16x4;
typedef __attribute__((ext_vector_type(4))) float f32x4;

#define MFMA16(a, b, c) __builtin_amdgcn_mfma_f32_16x16x32_bf16((a), (b), (c), 0, 0, 0)

__device__ __forceinline__ f32x4 mfma_k16(bf16x4 a, bf16x4 b, f32x4 c) {
#if __has_builtin(__builtin_amdgcn_mfma_f32_16x16x16bf16_1k)
  return __builtin_amdgcn_mfma_f32_16x16x16bf16_1k(a, b, c, 0, 0, 0);
#elif __has_builtin(__builtin_amdgcn_mfma_f32_16x16x16_bf16)
  return __builtin_amdgcn_mfma_f32_16x16x16_bf16(a, b, c, 0, 0, 0);
#else
  asm("v_mfma_f32_16x16x16_bf16 %0, %1, %2, %0" : "+v"(c) : "v"(a), "v"(b));
  return c;
#endif
}

__device__ __forceinline__ ushort f2bf(float f) {
  union { __hip_bfloat16 h; ushort u; } cv;
  cv.h = __float2bfloat16(f);
  return cv.u;
}

__device__ __forceinline__ void gload16(const void* g, void* l) {
  __builtin_amdgcn_global_load_lds((const __attribute__((address_space(1))) void*)g,
                                   (__attribute__((address_space(3))) void*)l, 16, 0, 0);
}

// ---------------- fp32 (K x N) -> bf16 transposed (N x K) ----------------
__global__ void wtrans_kernel(const float* __restrict__ W, ushort* __restrict__ Wt,
                              int K, int N) {
  __shared__ float t[32][33];
  const int tx = threadIdx.x & 31, ty = threadIdx.x >> 5;
  const int nb = blockIdx.x * 32, kb = blockIdx.y * 32;
#pragma unroll
  for (int i = 0; i < 4; ++i)
    t[ty + i * 8][tx] = W[(size_t)(kb + ty + i * 8) * N + nb + tx];
  __syncthreads();
#pragma unroll
  for (int i = 0; i < 4; ++i)
    Wt[(size_t)(nb + ty + i * 8) * K + kb + tx] = f2bf(t[tx][ty + i * 8]);
}

// ---------------- RMSNorm fp32 row(768) -> bf16 ----------------
__global__ void rmsnorm_kernel(const float* __restrict__ x, const float* __restrict__ g,
                               ushort* __restrict__ out) {
  const int row = blockIdx.x;
  const float* xr = x + (size_t)row * 768;
  const int t = threadIdx.x;
  float v0 = xr[t], v1 = xr[t + 256], v2 = xr[t + 512];
  float ss = v0 * v0 + v1 * v1 + v2 * v2;
#pragma unroll
  for (int off = 1; off < 64; off <<= 1) ss += __shfl_xor(ss, off);
  __shared__ float part[4];
  if ((t & 63) == 0) part[t >> 6] = ss;
  __syncthreads();
  const float tot = part[0] + part[1] + part[2] + part[3];
  const float r = rsqrtf(tot * (1.0f / 768.0f) + 1e-6f);
  ushort* orow = out + (size_t)row * 768;
  orow[t]       = f2bf(v0 * r * g[t]);
  orow[t + 256] = f2bf(v1 * r * g[t + 256]);
  orow[t + 512] = f2bf(v2 * r * g[t + 512]);
}

// ---------------- GEMM: C(MxN) = A(MxK,bf16) * Bt(NxK,bf16)^T ----------------
enum { EPI_BF16 = 0, EPI_VT = 1, EPI_RESID = 2, EPI_BIAS_GELU = 3, EPI_BIAS_RESID = 4 };

template <int EPI>
__global__ __launch_bounds__(256) void gemm_bt(
    const ushort* __restrict__ A, const ushort* __restrict__ Bt, void* __restrict__ Cout,
    const float* __restrict__ bias, const float* __restrict__ resid, int M, int N, int K,
    float scale) {
  __shared__ ushort As[128 * 64];
  __shared__ ushort Bs[128 * 64];
  const int tid = threadIdx.x;
  const int lane = tid & 63, wid = tid >> 6;
  const int wm = wid >> 1, wn = wid & 1;
  const int l15 = lane & 15, l4 = lane >> 4;
  const int m0 = blockIdx.y * 128, n0 = blockIdx.x * 128;
  const int srow = lane >> 3, sslot = lane & 7;
  const int skel = (sslot ^ srow) << 3;

  f32x4 acc[4][4] = {};

  for (int k0 = 0; k0 < K; k0 += 64) {
    __syncthreads();
#pragma unroll
    for (int i = 0; i < 4; ++i) {
      const int c = i * 4 + wid;
      const int row = c * 8 + srow;
      gload16(A + (size_t)(m0 + row) * K + k0 + skel, (char*)As + c * 1024);
      gload16(Bt + (size_t)(n0 + row) * K + k0 + skel, (char*)Bs + c * 1024);
    }
    __syncthreads();
#pragma unroll
    for (int ks = 0; ks < 2; ++ks) {
      bf16x8 af[4], bfr[4];
#pragma unroll
      for (int mi = 0; mi < 4; ++mi) {
        const int row = wm * 64 + mi * 16 + l15;
        const int slot = (ks * 4 + l4) ^ (row & 7);
        af[mi] = *(const bf16x8*)((const char*)As + row * 128 + slot * 16);
      }
#pragma unroll
      for (int ni = 0; ni < 4; ++ni) {
        const int row = wn * 64 + ni * 16 + l15;
        const int slot = (ks * 4 + l4) ^ (row & 7);
        bfr[ni] = *(const bf16x8*)((const char*)Bs + row * 128 + slot * 16);
      }
#pragma unroll
      for (int mi = 0; mi < 4; ++mi)
#pragma unroll
        for (int ni = 0; ni < 4; ++ni)
          acc[mi][ni] = MFMA16(af[mi], bfr[ni], acc[mi][ni]);
    }
  }

#pragma unroll
  for (int mi = 0; mi < 4; ++mi) {
#pragma unroll
    for (int ni = 0; ni < 4; ++ni) {
      const int gm = m0 + wm * 64 + mi * 16 + l4 * 4;
      const int gn = n0 + wn * 64 + ni * 16 + l15;
      f32x4 v = acc[mi][ni];
#pragma unroll
      for (int r = 0; r < 4; ++r) {
        const size_t idx = (size_t)(gm + r) * N + gn;
        const float f = v[r];
        if constexpr (EPI == EPI_BF16) {
          ((ushort*)Cout)[idx] = f2bf(f * scale);
        } else if constexpr (EPI == EPI_RESID) {
          ((float*)Cout)[idx] = f + resid[idx];
        } else if constexpr (EPI == EPI_BIAS_GELU) {
          const float u = f + bias[gn];
          const float gl = 0.5f * u * (1.0f + erff(u * 0.70710678118654752f));
          ((ushort*)Cout)[idx] = f2bf(gl);
        } else if constexpr (EPI == EPI_BIAS_RESID) {
          ((float*)Cout)[idx] = f + bias[gn] + resid[idx];
        }
      }
    }
  }
}

// ---------------- merged QKV GEMM: N=2304, segment epilogue ----------------
__global__ __launch_bounds__(256) void gemm_qkv(
    const ushort* __restrict__ A, const ushort* __restrict__ Bt,
    ushort* __restrict__ qout, ushort* __restrict__ kout, ushort* __restrict__ vtout,
    int M, int K, float qscale) {
  __shared__ ushort As[128 * 64];
  __shared__ ushort Bs[128 * 64];
  const int tid = threadIdx.x;
  const int lane = tid & 63, wid = tid >> 6;
  const int wm = wid >> 1, wn = wid & 1;
  const int l15 = lane & 15, l4 = lane >> 4;
  const int m0 = blockIdx.y * 128, n0 = blockIdx.x * 128;
  const int srow = lane >> 3, sslot = lane & 7;
  const int skel = (sslot ^ srow) << 3;

  f32x4 acc[4][4] = {};

  for (int k0 = 0; k0 < K; k0 += 64) {
    __syncthreads();
#pragma unroll
    for (int i = 0; i < 4; ++i) {
      const int c = i * 4 + wid;
      const int row = c * 8 + srow;
      gload16(A + (size_t)(m0 + row) * K + k0 + skel, (char*)As + c * 1024);
      gload16(Bt + (size_t)(n0 + row) * K + k0 + skel, (char*)Bs + c * 1024);
    }
    __syncthreads();
#pragma unroll
    for (int ks = 0; ks < 2; ++ks) {
      bf16x8 af[4], bfr[4];
#pragma unroll
      for (int mi = 0; mi < 4; ++mi) {
        const int row = wm * 64 + mi * 16 + l15;
        const int slot = (ks * 4 + l4) ^ (row & 7);
        af[mi] = *(const bf16x8*)((const char*)As + row * 128 + slot * 16);
      }
#pragma unroll
      for (int ni = 0; ni < 4; ++ni) {
        const int row = wn * 64 + ni * 16 + l15;
        const int slot = (ks * 4 + l4) ^ (row & 7);
        bfr[ni] = *(const bf16x8*)((const char*)Bs + row * 128 + slot * 16);
      }
#pragma unroll
      for (int mi = 0; mi < 4; ++mi)
#pragma unroll
        for (int ni = 0; ni < 4; ++ni)
          acc[mi][ni] = MFMA16(af[mi], bfr[ni], acc[mi][ni]);
    }
  }

  const int seg = n0 / 768;  // uniform per block (768 % 128 == 0)
#pragma unroll
  for (int mi = 0; mi < 4; ++mi) {
#pragma unroll
    for (int ni = 0; ni < 4; ++ni) {
      const int gm = m0 + wm * 64 + mi * 16 + l4 * 4;
      const int gn = n0 + wn * 64 + ni * 16 + l15;
      const int col = gn - seg * 768;
      f32x4 v = acc[mi][ni];
      if (seg == 0) {
#pragma unroll
        for (int r = 0; r < 4; ++r)
          qout[(size_t)(gm + r) * 768 + col] = f2bf(v[r] * qscale);
      } else if (seg == 1) {
#pragma unroll
        for (int r = 0; r < 4; ++r)
          kout[(size_t)(gm + r) * 768 + col] = f2bf(v[r]);
      } else {
        const int b = gm >> 12, tt = gm & 4095;
        const int h = col >> 6, dh = col & 63;
        ushort4 pk;
        pk.x = f2bf(v[0]); pk.y = f2bf(v[1]); pk.z = f2bf(v[2]); pk.w = f2bf(v[3]);
        *(ushort4*)(vtout + (((size_t)(b * 12 + h) * 64 + dh) * 4096 + tt)) = pk;
      }
    }
  }
}

// ---------------- causal MFMA flash attention (KVBLK=64, 32KB LDS) ----------
// Q,K row-major [B*T][768] bf16 (Q pre-scaled by 0.125/ln2); Vt [B][H][64][T].
// 16 q-rows/wave, 64 q/block, grid 64x24. Swapped QK^T; static max; deferred
// denominator. Double-buffered 64-key tiles -> 32KB LDS -> 5 blocks/CU.
__global__ __launch_bounds__(256, 5) void flash_attn_kernel(
    const ushort* __restrict__ Q, const ushort* __restrict__ Kb,
    const ushort* __restrict__ Vt, ushort* __restrict__ O) {
  __shared__ ushort Ks[2][64 * 64];   // [key][kd], 8-slot XOR swizzle
  __shared__ ushort Vts[2][64 * 64];  // [dh][key], 8-slot XOR swizzle
  const int tid = threadIdx.x, lane = tid & 63, wid = tid >> 6;
  const int l15 = lane & 15, l4 = lane >> 4;
  const int l7 = l15 & 7;
  const int bh = blockIdx.y, b = bh / 12, h = bh % 12;
  const int qb = 63 - (int)blockIdx.x;  // heavy blocks dispatched first
  const int qbase = qb * 64;
  const int q0 = qbase + wid * 16;

  bf16x8 qf0, qf1;
  {
    const ushort* qp = Q + ((size_t)(b * 4096 + q0 + l15) * 768 + h * 64 + l4 * 8);
    qf0 = *(const bf16x8*)qp;
    qf1 = *(const bf16x8*)(qp + 32);
  }
  f32x4 oo[4] = {};
  float dsum = 0.f;  // per-lane partial denominator for qrow = q0 + l15

  // staging: per issue, wave writes 1KB = 8 rows x 128B; source col pre-swizzled
  const int srow_l = lane >> 3;                  // row within 8-row group
  const int sco = ((lane & 7) ^ srow_l) << 3;    // swizzled source col offset (elems)
  const ushort* Kbase = Kb + (size_t)b * 4096 * 768 + h * 64;
  const ushort* Vbase = Vt + (size_t)bh * 64 * 4096;
  const int nt = qb + 1;

  // ct-invariant LDS read offsets (dt*16 and ct*16 are 0 mod 8)
  const int koff0 = l15 * 128 + ((l4 ^ l7) << 4);        // K frag, ks=0
  const int koff1 = l15 * 128 + (((4 + l4) ^ l7) << 4);  // K frag, ks=1
  const int vbase_off = l15 * 128 + ((l4 & 1) << 3);     // V frag base
  const int t2b = l4 >> 1;

  // ---- prologue: stage tile 0 into buffer 0 ----
#pragma unroll
  for (int i = 0; i < 2; ++i) {
    const int chunk = i * 4 + wid;            // 0..7, 8 rows each
    const int row = chunk * 8 + srow_l;
    gload16(Kbase + (size_t)row * 768 + sco, (char*)Ks[0] + chunk * 1024);
    gload16(Vbase + (size_t)row * 4096 + sco, (char*)Vts[0] + chunk * 1024);
  }

  int cur = 0;
  for (int kt = 0; kt < nt; ++kt) {
    const int k0 = kt << 6;
    if (kt + 1 < nt) {
      const int kn = (kt + 1) << 6;
#pragma unroll
      for (int i = 0; i < 2; ++i) {
        const int chunk = i * 4 + wid;
        const int row = chunk * 8 + srow_l;
        gload16(Kbase + (size_t)(kn + row) * 768 + sco,
                (char*)Ks[cur ^ 1] + chunk * 1024);
        gload16(Vbase + (size_t)row * 4096 + kn + sco,
                (char*)Vts[cur ^ 1] + chunk * 1024);
      }
      asm volatile("s_waitcnt vmcnt(4)" ::: "memory");  // current tile's loads done
    } else {
      asm volatile("s_waitcnt vmcnt(0)" ::: "memory");
    }
    __builtin_amdgcn_s_barrier();

    const int nf = (q0 + 16 - k0) >> 4;  // >= 1 always
    const int nct = nf < 4 ? nf : 4;
    const bool has_diag = (nf <= 4);
    const char* Kc = (const char*)Ks[cur];
    const char* Vc = (const char*)Vts[cur];

#pragma unroll
    for (int ct = 0; ct < 4; ++ct) {
      if (ct < nct) {
        // ---- S^T = mfma(K, Q): lane holds key=ct*16+l4*4+r, qrow=l15 ----
        f32x4 s = {0.f, 0.f, 0.f, 0.f};
        const bf16x8 kf0 = *(const bf16x8*)(Kc + ct * 2048 + koff0);
        const bf16x8 kf1 = *(const bf16x8*)(Kc + ct * 2048 + koff1);
        s = MFMA16(kf0, qf0, s);
        s = MFMA16(kf1, qf1, s);
        if (has_diag && ct == nct - 1) {
#pragma unroll
          for (int r = 0; r < 4; ++r)
            if (l4 * 4 + r > l15) s[r] = -30.f;  // exp2(-30) ~ 1e-9
        }
        // ---- exp2 + deferred denom + pack ----
        const float p0 = __builtin_amdgcn_exp2f(s[0]);
        const float p1 = __builtin_amdgcn_exp2f(s[1]);
        const float p2 = __builtin_amdgcn_exp2f(s[2]);
        const float p3 = __builtin_amdgcn_exp2f(s[3]);
        dsum += (p0 + p1) + (p2 + p3);
        union { bf16x4 v; ushort u[4]; } pk;
        pk.u[0] = f2bf(p0); pk.u[1] = f2bf(p1);
        pk.u[2] = f2bf(p2); pk.u[3] = f2bf(p3);
        // ---- PV: P stays in registers; V frag = 4 consecutive keys ----
        const int xo = ((2 * ct + t2b) ^ l7) << 4;
#pragma unroll
        for (int dt = 0; dt < 4; ++dt) {
          const bf16x4 vf = *(const bf16x4*)(Vc + dt * 2048 + vbase_off + xo);
          oo[dt] = mfma_k16(pk.v, vf, oo[dt]);
        }
      }
    }
    asm volatile("" ::: "memory");
    __builtin_amdgcn_s_barrier();
    cur ^= 1;
  }

  // ---- final denominator reduce + normalize + store ----
  dsum += __shfl_xor(dsum, 16);
  dsum += __shfl_xor(dsum, 32);  // all l4-copies now hold full denom(q0+l15)
  ushort* op = O + ((size_t)(b * 4096 + q0 + l4 * 4) * 768 + h * 64);
#pragma unroll
  for (int r = 0; r < 4; ++r) {
    const float inv = 1.0f / __shfl(dsum, l4 * 4 + r);
#pragma unroll
    for (int dt = 0; dt < 4; ++dt)
      op[(size_t)r * 768 + dt * 16 + l15] = f2bf(oo[dt][r] * inv);
  }
}

extern "C" void kernel_launch(void* const* d_in, const int* in_sizes, int n_in,
                              void* d_out, int out_size, void* d_ws, size_t ws_size,
                              hipStream_t stream) {
  const float* x  = (const float*)d_in[0];
  const float* wq = (const float*)d_in[1];
  const float* wk = (const float*)d_in[2];
  const float* wv = (const float*)d_in[3];
  const float* wo = (const float*)d_in[4];
  const float* w1 = (const float*)d_in[5];
  const float* b1 = (const float*)d_in[6];
  const float* w2 = (const float*)d_in[7];
  const float* b2 = (const float*)d_in[8];
  const float* g1 = (const float*)d_in[9];
  const float* g2 = (const float*)d_in[10];
  float* out = (float*)d_out;

  char* p = (char*)d_ws;
  ushort* wqT = (ushort*)p; p += (size_t)768 * 768 * 2;   // } contiguous: acts as
  ushort* wkT = (ushort*)p; p += (size_t)768 * 768 * 2;   // } one 2304x768 B matrix
  ushort* wvT = (ushort*)p; p += (size_t)768 * 768 * 2;   // } for merged QKV GEMM
  ushort* woT = (ushort*)p; p += (size_t)768 * 768 * 2;
  ushort* w1T = (ushort*)p; p += (size_t)3072 * 768 * 2;
  ushort* w2T = (ushort*)p; p += (size_t)768 * 3072 * 2;
  ushort* xn  = (ushort*)p; p += (size_t)8192 * 768 * 2;
  ushort* qb  = (ushort*)p; p += (size_t)8192 * 768 * 2;
  ushort* kb  = (ushort*)p; p += (size_t)8192 * 768 * 2;
  ushort* vtb = (ushort*)p; p += (size_t)8192 * 768 * 2;
  ushort* attn = (ushort*)p; p += (size_t)8192 * 768 * 2;
  float* x2 = (float*)p; p += (size_t)8192 * 768 * 4;
  ushort* hf = qb;  // reuse qb..attn region (exactly 8192*3072*2 bytes)

  // Q pre-scale folds 1/sqrt(64) and 1/ln2 (softmax computed in exp2 units)
  const float qscale = 0.125f * 1.44269504088896340736f;

  dim3 blk(256);
  wtrans_kernel<<<dim3(24, 24), blk, 0, stream>>>(wq, wqT, 768, 768);
  wtrans_kernel<<<dim3(24, 24), blk, 0, stream>>>(wk, wkT, 768, 768);
  wtrans_kernel<<<dim3(24, 24), blk, 0, stream>>>(wv, wvT, 768, 768);
  wtrans_kernel<<<dim3(24, 24), blk, 0, stream>>>(wo, woT, 768, 768);
  wtrans_kernel<<<dim3(96, 24), blk, 0, stream>>>(w1, w1T, 768, 3072);
  wtrans_kernel<<<dim3(24, 96), blk, 0, stream>>>(w2, w2T, 3072, 768);

  rmsnorm_kernel<<<8192, blk, 0, stream>>>(x, g1, xn);

  gemm_qkv<<<dim3(18, 64), blk, 0, stream>>>(xn, wqT, qb, kb, vtb, 8192, 768, qscale);

  flash_attn_kernel<<<dim3(64, 24), blk, 0, stream>>>(qb, kb, vtb, attn);

  gemm_bt<EPI_RESID><<<dim3(6, 64), blk, 0, stream>>>(attn, woT, x2, nullptr, x, 8192, 768, 768, 1.0f);

  rmsnorm_kernel<<<8192, blk, 0, stream>>>(x2, g2, xn);

  gemm_bt<EPI_BIAS_GELU><<<dim3(24, 64), blk, 0, stream>>>(xn, w1T, hf, b1, nullptr, 8192, 3072, 768, 1.0f);
  gemm_bt<EPI_BIAS_RESID><<<dim3(6, 64), blk, 0, stream>>>(hf, w2T, out, b2, x2, 8192, 768, 3072, 1.0f);
}

// Round 7
// 353.703 us; speedup vs baseline: 1.6299x; 1.1644x over previous
//
#include <hip/hip_runtime.h>
#include <hip/hip_bf16.h>

typedef __attribute__((ext_vector_type(8))) short bf16x8;
typedef __attribute__((ext_vector_type(4))) short bf16x4;
typedef __attribute__((ext_vector_type(4))) float f32x4;

#define MFMA16(a, b, c) __builtin_amdgcn_mfma_f32_16x16x32_bf16((a), (b), (c), 0, 0, 0)

__device__ __forceinline__ f32x4 mfma_k16(bf16x4 a, bf16x4 b, f32x4 c) {
#if __has_builtin(__builtin_amdgcn_mfma_f32_16x16x16bf16_1k)
  return __builtin_amdgcn_mfma_f32_16x16x16bf16_1k(a, b, c, 0, 0, 0);
#elif __has_builtin(__builtin_amdgcn_mfma_f32_16x16x16_bf16)
  return __builtin_amdgcn_mfma_f32_16x16x16_bf16(a, b, c, 0, 0, 0);
#else
  asm("v_mfma_f32_16x16x16_bf16 %0, %1, %2, %0" : "+v"(c) : "v"(a), "v"(b));
  return c;
#endif
}

__device__ __forceinline__ ushort f2bf(float f) {
  union { __hip_bfloat16 h; ushort u; } cv;
  cv.h = __float2bfloat16(f);
  return cv.u;
}

__device__ __forceinline__ void gload16(const void* g, void* l) {
  __builtin_amdgcn_global_load_lds((const __attribute__((address_space(1))) void*)g,
                                   (__attribute__((address_space(3))) void*)l, 16, 0, 0);
}

// ---------------- fp32 (K x N) -> bf16 transposed (N x K) ----------------
__global__ void wtrans_kernel(const float* __restrict__ W, ushort* __restrict__ Wt,
                              int K, int N) {
  __shared__ float t[32][33];
  const int tx = threadIdx.x & 31, ty = threadIdx.x >> 5;
  const int nb = blockIdx.x * 32, kb = blockIdx.y * 32;
#pragma unroll
  for (int i = 0; i < 4; ++i)
    t[ty + i * 8][tx] = W[(size_t)(kb + ty + i * 8) * N + nb + tx];
  __syncthreads();
#pragma unroll
  for (int i = 0; i < 4; ++i)
    Wt[(size_t)(nb + ty + i * 8) * K + kb + tx] = f2bf(t[tx][ty + i * 8]);
}

// ---------------- RMSNorm fp32 row(768) -> bf16 ----------------
__global__ void rmsnorm_kernel(const float* __restrict__ x, const float* __restrict__ g,
                               ushort* __restrict__ out) {
  const int row = blockIdx.x;
  const float* xr = x + (size_t)row * 768;
  const int t = threadIdx.x;
  float v0 = xr[t], v1 = xr[t + 256], v2 = xr[t + 512];
  float ss = v0 * v0 + v1 * v1 + v2 * v2;
#pragma unroll
  for (int off = 1; off < 64; off <<= 1) ss += __shfl_xor(ss, off);
  __shared__ float part[4];
  if ((t & 63) == 0) part[t >> 6] = ss;
  __syncthreads();
  const float tot = part[0] + part[1] + part[2] + part[3];
  const float r = rsqrtf(tot * (1.0f / 768.0f) + 1e-6f);
  ushort* orow = out + (size_t)row * 768;
  orow[t]       = f2bf(v0 * r * g[t]);
  orow[t + 256] = f2bf(v1 * r * g[t + 256]);
  orow[t + 512] = f2bf(v2 * r * g[t + 512]);
}

// ---------------- GEMM: C(MxN) = A(MxK,bf16) * Bt(NxK,bf16)^T ----------------
enum { EPI_BF16 = 0, EPI_VT = 1, EPI_RESID = 2, EPI_BIAS_GELU = 3, EPI_BIAS_RESID = 4 };

template <int EPI>
__global__ __launch_bounds__(256) void gemm_bt(
    const ushort* __restrict__ A, const ushort* __restrict__ Bt, void* __restrict__ Cout,
    const float* __restrict__ bias, const float* __restrict__ resid, int M, int N, int K,
    float scale) {
  __shared__ ushort As[128 * 64];
  __shared__ ushort Bs[128 * 64];
  const int tid = threadIdx.x;
  const int lane = tid & 63, wid = tid >> 6;
  const int wm = wid >> 1, wn = wid & 1;
  const int l15 = lane & 15, l4 = lane >> 4;
  const int m0 = blockIdx.y * 128, n0 = blockIdx.x * 128;
  const int srow = lane >> 3, sslot = lane & 7;
  const int skel = (sslot ^ srow) << 3;

  f32x4 acc[4][4] = {};

  for (int k0 = 0; k0 < K; k0 += 64) {
    __syncthreads();
#pragma unroll
    for (int i = 0; i < 4; ++i) {
      const int c = i * 4 + wid;
      const int row = c * 8 + srow;
      gload16(A + (size_t)(m0 + row) * K + k0 + skel, (char*)As + c * 1024);
      gload16(Bt + (size_t)(n0 + row) * K + k0 + skel, (char*)Bs + c * 1024);
    }
    __syncthreads();
#pragma unroll
    for (int ks = 0; ks < 2; ++ks) {
      bf16x8 af[4], bfr[4];
#pragma unroll
      for (int mi = 0; mi < 4; ++mi) {
        const int row = wm * 64 + mi * 16 + l15;
        const int slot = (ks * 4 + l4) ^ (row & 7);
        af[mi] = *(const bf16x8*)((const char*)As + row * 128 + slot * 16);
      }
#pragma unroll
      for (int ni = 0; ni < 4; ++ni) {
        const int row = wn * 64 + ni * 16 + l15;
        const int slot = (ks * 4 + l4) ^ (row & 7);
        bfr[ni] = *(const bf16x8*)((const char*)Bs + row * 128 + slot * 16);
      }
#pragma unroll
      for (int mi = 0; mi < 4; ++mi)
#pragma unroll
        for (int ni = 0; ni < 4; ++ni)
          acc[mi][ni] = MFMA16(af[mi], bfr[ni], acc[mi][ni]);
    }
  }

#pragma unroll
  for (int mi = 0; mi < 4; ++mi) {
#pragma unroll
    for (int ni = 0; ni < 4; ++ni) {
      const int gm = m0 + wm * 64 + mi * 16 + l4 * 4;
      const int gn = n0 + wn * 64 + ni * 16 + l15;
      f32x4 v = acc[mi][ni];
#pragma unroll
      for (int r = 0; r < 4; ++r) {
        const size_t idx = (size_t)(gm + r) * N + gn;
        const float f = v[r];
        if constexpr (EPI == EPI_BF16) {
          ((ushort*)Cout)[idx] = f2bf(f * scale);
        } else if constexpr (EPI == EPI_RESID) {
          ((float*)Cout)[idx] = f + resid[idx];
        } else if constexpr (EPI == EPI_BIAS_GELU) {
          const float u = f + bias[gn];
          const float gl = 0.5f * u * (1.0f + erff(u * 0.70710678118654752f));
          ((ushort*)Cout)[idx] = f2bf(gl);
        } else if constexpr (EPI == EPI_BIAS_RESID) {
          ((float*)Cout)[idx] = f + bias[gn] + resid[idx];
        }
      }
    }
  }
}

// ---------------- merged QKV GEMM: N=2304, segment epilogue ----------------
__global__ __launch_bounds__(256) void gemm_qkv(
    const ushort* __restrict__ A, const ushort* __restrict__ Bt,
    ushort* __restrict__ qout, ushort* __restrict__ kout, ushort* __restrict__ vtout,
    int M, int K, float qscale) {
  __shared__ ushort As[128 * 64];
  __shared__ ushort Bs[128 * 64];
  const int tid = threadIdx.x;
  const int lane = tid & 63, wid = tid >> 6;
  const int wm = wid >> 1, wn = wid & 1;
  const int l15 = lane & 15, l4 = lane >> 4;
  const int m0 = blockIdx.y * 128, n0 = blockIdx.x * 128;
  const int srow = lane >> 3, sslot = lane & 7;
  const int skel = (sslot ^ srow) << 3;

  f32x4 acc[4][4] = {};

  for (int k0 = 0; k0 < K; k0 += 64) {
    __syncthreads();
#pragma unroll
    for (int i = 0; i < 4; ++i) {
      const int c = i * 4 + wid;
      const int row = c * 8 + srow;
      gload16(A + (size_t)(m0 + row) * K + k0 + skel, (char*)As + c * 1024);
      gload16(Bt + (size_t)(n0 + row) * K + k0 + skel, (char*)Bs + c * 1024);
    }
    __syncthreads();
#pragma unroll
    for (int ks = 0; ks < 2; ++ks) {
      bf16x8 af[4], bfr[4];
#pragma unroll
      for (int mi = 0; mi < 4; ++mi) {
        const int row = wm * 64 + mi * 16 + l15;
        const int slot = (ks * 4 + l4) ^ (row & 7);
        af[mi] = *(const bf16x8*)((const char*)As + row * 128 + slot * 16);
      }
#pragma unroll
      for (int ni = 0; ni < 4; ++ni) {
        const int row = wn * 64 + ni * 16 + l15;
        const int slot = (ks * 4 + l4) ^ (row & 7);
        bfr[ni] = *(const bf16x8*)((const char*)Bs + row * 128 + slot * 16);
      }
#pragma unroll
      for (int mi = 0; mi < 4; ++mi)
#pragma unroll
        for (int ni = 0; ni < 4; ++ni)
          acc[mi][ni] = MFMA16(af[mi], bfr[ni], acc[mi][ni]);
    }
  }

  const int seg = n0 / 768;  // uniform per block (768 % 128 == 0)
#pragma unroll
  for (int mi = 0; mi < 4; ++mi) {
#pragma unroll
    for (int ni = 0; ni < 4; ++ni) {
      const int gm = m0 + wm * 64 + mi * 16 + l4 * 4;
      const int gn = n0 + wn * 64 + ni * 16 + l15;
      const int col = gn - seg * 768;
      f32x4 v = acc[mi][ni];
      if (seg == 0) {
#pragma unroll
        for (int r = 0; r < 4; ++r)
          qout[(size_t)(gm + r) * 768 + col] = f2bf(v[r] * qscale);
      } else if (seg == 1) {
#pragma unroll
        for (int r = 0; r < 4; ++r)
          kout[(size_t)(gm + r) * 768 + col] = f2bf(v[r]);
      } else {
        const int b = gm >> 12, tt = gm & 4095;
        const int h = col >> 6, dh = col & 63;
        ushort4 pk;
        pk.x = f2bf(v[0]); pk.y = f2bf(v[1]); pk.z = f2bf(v[2]); pk.w = f2bf(v[3]);
        *(ushort4*)(vtout + (((size_t)(b * 12 + h) * 64 + dh) * 4096 + tt)) = pk;
      }
    }
  }
}

// ---------------- causal MFMA flash attention (KVBLK=64, XCD-clustered) ------
// Q,K row-major [B*T][768] bf16 (Q pre-scaled by 0.125/ln2); Vt [B][H][64][T].
// 16 q-rows/wave, 64 q/block, 1536 blocks. Chunked XCD swizzle: each XCD owns
// 3 whole (b,h) columns -> K/V working set 3MB fits its 4MB L2. Swapped QK^T,
// static max, deferred denominator, double-buffered, counted vmcnt, setprio.
__global__ __launch_bounds__(256, 5) void flash_attn_kernel(
    const ushort* __restrict__ Q, const ushort* __restrict__ Kb,
    const ushort* __restrict__ Vt, ushort* __restrict__ O) {
  __shared__ ushort Ks[2][64 * 64];   // [key][kd], 8-slot XOR swizzle
  __shared__ ushort Vts[2][64 * 64];  // [dh][key], 8-slot XOR swizzle
  const int tid = threadIdx.x, lane = tid & 63, wid = tid >> 6;
  const int l15 = lane & 15, l4 = lane >> 4;
  const int l7 = l15 & 7;
  // chunked XCD swizzle: 1536 blocks, 8 XCDs -> 192-block chunks (3 bh-columns)
  const int bid = (int)blockIdx.x;
  const int idx = (bid & 7) * 192 + (bid >> 3);
  const int bh = idx >> 6, b = bh / 12, h = bh % 12;
  const int qb = 63 - (idx & 63);  // heavy blocks first within each column
  const int qbase = qb * 64;
  const int q0 = qbase + wid * 16;

  bf16x8 qf0, qf1;
  {
    const ushort* qp = Q + ((size_t)(b * 4096 + q0 + l15) * 768 + h * 64 + l4 * 8);
    qf0 = *(const bf16x8*)qp;
    qf1 = *(const bf16x8*)(qp + 32);
  }
  f32x4 oo[4] = {};
  float dsum = 0.f;  // per-lane partial denominator for qrow = q0 + l15

  // staging: persistent per-lane pointers, advanced by uniform strides
  const int srow_l = lane >> 3;                // row within 8-row group
  const int sco = ((lane & 7) ^ srow_l) << 3;  // swizzled source col offset (elems)
  const ushort* Kbase = Kb + (size_t)b * 4096 * 768 + h * 64;
  const ushort* Vbase = Vt + (size_t)bh * 64 * 4096;
  const int c0 = wid, c1 = 4 + wid;  // this wave's two 8-row chunks
  const ushort* kp0 = Kbase + (size_t)(c0 * 8 + srow_l) * 768 + sco;
  const ushort* kp1 = Kbase + (size_t)(c1 * 8 + srow_l) * 768 + sco;
  const ushort* vp0 = Vbase + (size_t)(c0 * 8 + srow_l) * 4096 + sco;
  const ushort* vp1 = Vbase + (size_t)(c1 * 8 + srow_l) * 4096 + sco;
  const int nt = qb + 1;

  // ct-invariant LDS read offsets (dt*16 and ct*16 are 0 mod 8)
  const int koff0 = l15 * 128 + ((l4 ^ l7) << 4);        // K frag, ks=0
  const int koff1 = l15 * 128 + (((4 + l4) ^ l7) << 4);  // K frag, ks=1
  const int vbase_off = l15 * 128 + ((l4 & 1) << 3);     // V frag base
  const int t2b = l4 >> 1;

  // ---- prologue: stage tile 0 into buffer 0 ----
  gload16(kp0, (char*)Ks + c0 * 1024);
  gload16(kp1, (char*)Ks + c1 * 1024);
  gload16(vp0, (char*)Vts + c0 * 1024);
  gload16(vp1, (char*)Vts + c1 * 1024);

  int cur = 0;
  for (int kt = 0; kt < nt; ++kt) {
    const int k0 = kt << 6;
    if (kt + 1 < nt) {
      kp0 += 64 * 768; kp1 += 64 * 768;  // next 64 keys
      vp0 += 64; vp1 += 64;              // next 64 t-columns
      const int nb = (cur ^ 1) * 8192;
      gload16(kp0, (char*)Ks + nb + c0 * 1024);
      gload16(kp1, (char*)Ks + nb + c1 * 1024);
      gload16(vp0, (char*)Vts + nb + c0 * 1024);
      gload16(vp1, (char*)Vts + nb + c1 * 1024);
      asm volatile("s_waitcnt vmcnt(4)" ::: "memory");  // current tile's loads done
    } else {
      asm volatile("s_waitcnt vmcnt(0)" ::: "memory");
    }
    __builtin_amdgcn_s_barrier();

    const int nf = (q0 + 16 - k0) >> 4;  // >= 1 always
    const int nct = nf < 4 ? nf : 4;
    const bool has_diag = (nf <= 4);
    const char* Kc = (const char*)Ks + cur * 8192;
    const char* Vc = (const char*)Vts + cur * 8192;

    __builtin_amdgcn_s_setprio(1);
#pragma unroll
    for (int ct = 0; ct < 4; ++ct) {
      if (ct < nct) {
        // ---- S^T = mfma(K, Q): lane holds key=ct*16+l4*4+r, qrow=l15 ----
        f32x4 s = {0.f, 0.f, 0.f, 0.f};
        const bf16x8 kf0 = *(const bf16x8*)(Kc + ct * 2048 + koff0);
        const bf16x8 kf1 = *(const bf16x8*)(Kc + ct * 2048 + koff1);
        s = MFMA16(kf0, qf0, s);
        s = MFMA16(kf1, qf1, s);
        if (has_diag && ct == nct - 1) {
#pragma unroll
          for (int r = 0; r < 4; ++r)
            if (l4 * 4 + r > l15) s[r] = -30.f;  // exp2(-30) ~ 1e-9
        }
        // ---- exp2 + deferred denom + pack ----
        const float p0 = __builtin_amdgcn_exp2f(s[0]);
        const float p1 = __builtin_amdgcn_exp2f(s[1]);
        const float p2 = __builtin_amdgcn_exp2f(s[2]);
        const float p3 = __builtin_amdgcn_exp2f(s[3]);
        dsum += (p0 + p1) + (p2 + p3);
        union { bf16x4 v; ushort u[4]; } pk;
        pk.u[0] = f2bf(p0); pk.u[1] = f2bf(p1);
        pk.u[2] = f2bf(p2); pk.u[3] = f2bf(p3);
        // ---- PV: P stays in registers; V frag = 4 consecutive keys ----
        const int xo = ((2 * ct + t2b) ^ l7) << 4;
#pragma unroll
        for (int dt = 0; dt < 4; ++dt) {
          const bf16x4 vf = *(const bf16x4*)(Vc + dt * 2048 + vbase_off + xo);
          oo[dt] = mfma_k16(pk.v, vf, oo[dt]);
        }
      }
    }
    __builtin_amdgcn_s_setprio(0);
    asm volatile("" ::: "memory");
    __builtin_amdgcn_s_barrier();
    cur ^= 1;
  }

  // ---- final denominator reduce + normalize + store ----
  dsum += __shfl_xor(dsum, 16);
  dsum += __shfl_xor(dsum, 32);  // all l4-copies now hold full denom(q0+l15)
  ushort* op = O + ((size_t)(b * 4096 + q0 + l4 * 4) * 768 + h * 64);
#pragma unroll
  for (int r = 0; r < 4; ++r) {
    const float inv = 1.0f / __shfl(dsum, l4 * 4 + r);
#pragma unroll
    for (int dt = 0; dt < 4; ++dt)
      op[(size_t)r * 768 + dt * 16 + l15] = f2bf(oo[dt][r] * inv);
  }
}

extern "C" void kernel_launch(void* const* d_in, const int* in_sizes, int n_in,
                              void* d_out, int out_size, void* d_ws, size_t ws_size,
                              hipStream_t stream) {
  const float* x  = (const float*)d_in[0];
  const float* wq = (const float*)d_in[1];
  const float* wk = (const float*)d_in[2];
  const float* wv = (const float*)d_in[3];
  const float* wo = (const float*)d_in[4];
  const float* w1 = (const float*)d_in[5];
  const float* b1 = (const float*)d_in[6];
  const float* w2 = (const float*)d_in[7];
  const float* b2 = (const float*)d_in[8];
  const float* g1 = (const float*)d_in[9];
  const float* g2 = (const float*)d_in[10];
  float* out = (float*)d_out;

  char* p = (char*)d_ws;
  ushort* wqT = (ushort*)p; p += (size_t)768 * 768 * 2;   // } contiguous: acts as
  ushort* wkT = (ushort*)p; p += (size_t)768 * 768 * 2;   // } one 2304x768 B matrix
  ushort* wvT = (ushort*)p; p += (size_t)768 * 768 * 2;   // } for merged QKV GEMM
  ushort* woT = (ushort*)p; p += (size_t)768 * 768 * 2;
  ushort* w1T = (ushort*)p; p += (size_t)3072 * 768 * 2;
  ushort* w2T = (ushort*)p; p += (size_t)768 * 3072 * 2;
  ushort* xn  = (ushort*)p; p += (size_t)8192 * 768 * 2;
  ushort* qb  = (ushort*)p; p += (size_t)8192 * 768 * 2;
  ushort* kb  = (ushort*)p; p += (size_t)8192 * 768 * 2;
  ushort* vtb = (ushort*)p; p += (size_t)8192 * 768 * 2;
  ushort* attn = (ushort*)p; p += (size_t)8192 * 768 * 2;
  float* x2 = (float*)p; p += (size_t)8192 * 768 * 4;
  ushort* hf = qb;  // reuse qb..attn region (exactly 8192*3072*2 bytes)

  // Q pre-scale folds 1/sqrt(64) and 1/ln2 (softmax computed in exp2 units)
  const float qscale = 0.125f * 1.44269504088896340736f;

  dim3 blk(256);
  wtrans_kernel<<<dim3(24, 24), blk, 0, stream>>>(wq, wqT, 768, 768);
  wtrans_kernel<<<dim3(24, 24), blk, 0, stream>>>(wk, wkT, 768, 768);
  wtrans_kernel<<<dim3(24, 24), blk, 0, stream>>>(wv, wvT, 768, 768);
  wtrans_kernel<<<dim3(24, 24), blk, 0, stream>>>(wo, woT, 768, 768);
  wtrans_kernel<<<dim3(96, 24), blk, 0, stream>>>(w1, w1T, 768, 3072);
  wtrans_kernel<<<dim3(24, 96), blk, 0, stream>>>(w2, w2T, 3072, 768);

  rmsnorm_kernel<<<8192, blk, 0, stream>>>(x, g1, xn);

  gemm_qkv<<<dim3(18, 64), blk, 0, stream>>>(xn, wqT, qb, kb, vtb, 8192, 768, qscale);

  flash_attn_kernel<<<dim3(1536), blk, 0, stream>>>(qb, kb, vtb, attn);

  gemm_bt<EPI_RESID><<<dim3(6, 64), blk, 0, stream>>>(attn, woT, x2, nullptr, x, 8192, 768, 768, 1.0f);

  rmsnorm_kernel<<<8192, blk, 0, stream>>>(x2, g2, xn);

  gemm_bt<EPI_BIAS_GELU><<<dim3(24, 64), blk, 0, stream>>>(xn, w1T, hf, b1, nullptr, 8192, 3072, 768, 1.0f);
  gemm_bt<EPI_BIAS_RESID><<<dim3(6, 64), blk, 0, stream>>>(hf, w2T, out, b2, x2, 8192, 768, 3072, 1.0f);
}

// Round 8
// 342.632 us; speedup vs baseline: 1.6826x; 1.0323x over previous
//
#include <hip/hip_runtime.h>
#include <hip/hip_bf16.h>

typedef __attribute__((ext_vector_type(8))) short bf16x8;
typedef __attribute__((ext_vector_type(4))) short bf16x4;
typedef __attribute__((ext_vector_type(4))) float f32x4;

#define MFMA16(a, b, c) __builtin_amdgcn_mfma_f32_16x16x32_bf16((a), (b), (c), 0, 0, 0)

__device__ __forceinline__ f32x4 mfma_k16(bf16x4 a, bf16x4 b, f32x4 c) {
#if __has_builtin(__builtin_amdgcn_mfma_f32_16x16x16bf16_1k)
  return __builtin_amdgcn_mfma_f32_16x16x16bf16_1k(a, b, c, 0, 0, 0);
#elif __has_builtin(__builtin_amdgcn_mfma_f32_16x16x16_bf16)
  return __builtin_amdgcn_mfma_f32_16x16x16_bf16(a, b, c, 0, 0, 0);
#else
  asm("v_mfma_f32_16x16x16_bf16 %0, %1, %2, %0" : "+v"(c) : "v"(a), "v"(b));
  return c;
#endif
}

__device__ __forceinline__ ushort f2bf(float f) {
  union { __hip_bfloat16 h; ushort u; } cv;
  cv.h = __float2bfloat16(f);
  return cv.u;
}

__device__ __forceinline__ void gload16(const void* g, void* l) {
  __builtin_amdgcn_global_load_lds((const __attribute__((address_space(1))) void*)g,
                                   (__attribute__((address_space(3))) void*)l, 16, 0, 0);
}

// ---------------- merged weight transpose+cast: all 6 matrices ----------------
__global__ void wtrans_all(const float* __restrict__ wq, const float* __restrict__ wk,
                           const float* __restrict__ wv, const float* __restrict__ wo,
                           const float* __restrict__ w1, const float* __restrict__ w2,
                           ushort* __restrict__ wqT, ushort* __restrict__ wkT,
                           ushort* __restrict__ wvT, ushort* __restrict__ woT,
                           ushort* __restrict__ w1T, ushort* __restrict__ w2T) {
  __shared__ float t[32][33];
  int id = blockIdx.x;
  const float* W;
  ushort* Wt;
  int K, N, nbx;
  if (id < 2304) {  // 4 square 768x768 matrices, 576 tiles each
    const int m = id / 576;
    id -= m * 576;
    W = (m == 0) ? wq : (m == 1) ? wk : (m == 2) ? wv : wo;
    Wt = (m == 0) ? wqT : (m == 1) ? wkT : (m == 2) ? wvT : woT;
    K = 768; N = 768; nbx = 24;
  } else if (id < 4608) {
    id -= 2304; W = w1; Wt = w1T; K = 768; N = 3072; nbx = 96;
  } else {
    id -= 4608; W = w2; Wt = w2T; K = 3072; N = 768; nbx = 24;
  }
  const int nb = (id % nbx) * 32, kb = (id / nbx) * 32;
  const int tx = threadIdx.x & 31, ty = threadIdx.x >> 5;
#pragma unroll
  for (int i = 0; i < 4; ++i)
    t[ty + i * 8][tx] = W[(size_t)(kb + ty + i * 8) * N + nb + tx];
  __syncthreads();
#pragma unroll
  for (int i = 0; i < 4; ++i)
    Wt[(size_t)(nb + ty + i * 8) * K + kb + tx] = f2bf(t[tx][ty + i * 8]);
}

// ---------------- RMSNorm fp32 row(768) -> bf16 ----------------
__global__ void rmsnorm_kernel(const float* __restrict__ x, const float* __restrict__ g,
                               ushort* __restrict__ out) {
  const int row = blockIdx.x;
  const float* xr = x + (size_t)row * 768;
  const int t = threadIdx.x;
  float v0 = xr[t], v1 = xr[t + 256], v2 = xr[t + 512];
  float ss = v0 * v0 + v1 * v1 + v2 * v2;
#pragma unroll
  for (int off = 1; off < 64; off <<= 1) ss += __shfl_xor(ss, off);
  __shared__ float part[4];
  if ((t & 63) == 0) part[t >> 6] = ss;
  __syncthreads();
  const float tot = part[0] + part[1] + part[2] + part[3];
  const float r = rsqrtf(tot * (1.0f / 768.0f) + 1e-6f);
  ushort* orow = out + (size_t)row * 768;
  orow[t]       = f2bf(v0 * r * g[t]);
  orow[t + 256] = f2bf(v1 * r * g[t + 256]);
  orow[t + 512] = f2bf(v2 * r * g[t + 512]);
}

// ---------------- GEMM: C(MxN) = A(MxK,bf16) * Bt(NxK,bf16)^T ----------------
enum { EPI_BF16 = 0, EPI_VT = 1, EPI_RESID = 2, EPI_BIAS_GELU = 3, EPI_BIAS_RESID = 4 };

template <int EPI>
__global__ __launch_bounds__(256) void gemm_bt(
    const ushort* __restrict__ A, const ushort* __restrict__ Bt, void* __restrict__ Cout,
    const float* __restrict__ bias, const float* __restrict__ resid, int M, int N, int K,
    float scale) {
  __shared__ ushort As[128 * 64];
  __shared__ ushort Bs[128 * 64];
  const int tid = threadIdx.x;
  const int lane = tid & 63, wid = tid >> 6;
  const int wm = wid >> 1, wn = wid & 1;
  const int l15 = lane & 15, l4 = lane >> 4;
  const int m0 = blockIdx.y * 128, n0 = blockIdx.x * 128;
  const int srow = lane >> 3, sslot = lane & 7;
  const int skel = (sslot ^ srow) << 3;

  f32x4 acc[4][4] = {};

  for (int k0 = 0; k0 < K; k0 += 64) {
    __syncthreads();
#pragma unroll
    for (int i = 0; i < 4; ++i) {
      const int c = i * 4 + wid;
      const int row = c * 8 + srow;
      gload16(A + (size_t)(m0 + row) * K + k0 + skel, (char*)As + c * 1024);
      gload16(Bt + (size_t)(n0 + row) * K + k0 + skel, (char*)Bs + c * 1024);
    }
    __syncthreads();
#pragma unroll
    for (int ks = 0; ks < 2; ++ks) {
      bf16x8 af[4], bfr[4];
#pragma unroll
      for (int mi = 0; mi < 4; ++mi) {
        const int row = wm * 64 + mi * 16 + l15;
        const int slot = (ks * 4 + l4) ^ (row & 7);
        af[mi] = *(const bf16x8*)((const char*)As + row * 128 + slot * 16);
      }
#pragma unroll
      for (int ni = 0; ni < 4; ++ni) {
        const int row = wn * 64 + ni * 16 + l15;
        const int slot = (ks * 4 + l4) ^ (row & 7);
        bfr[ni] = *(const bf16x8*)((const char*)Bs + row * 128 + slot * 16);
      }
#pragma unroll
      for (int mi = 0; mi < 4; ++mi)
#pragma unroll
        for (int ni = 0; ni < 4; ++ni)
          acc[mi][ni] = MFMA16(af[mi], bfr[ni], acc[mi][ni]);
    }
  }

#pragma unroll
  for (int mi = 0; mi < 4; ++mi) {
#pragma unroll
    for (int ni = 0; ni < 4; ++ni) {
      const int gm = m0 + wm * 64 + mi * 16 + l4 * 4;
      const int gn = n0 + wn * 64 + ni * 16 + l15;
      f32x4 v = acc[mi][ni];
#pragma unroll
      for (int r = 0; r < 4; ++r) {
        const size_t idx = (size_t)(gm + r) * N + gn;
        const float f = v[r];
        if constexpr (EPI == EPI_BF16) {
          ((ushort*)Cout)[idx] = f2bf(f * scale);
        } else if constexpr (EPI == EPI_RESID) {
          ((float*)Cout)[idx] = f + resid[idx];
        } else if constexpr (EPI == EPI_BIAS_GELU) {
          const float u = f + bias[gn];
          const float gl = 0.5f * u * (1.0f + erff(u * 0.70710678118654752f));
          ((ushort*)Cout)[idx] = f2bf(gl);
        } else if constexpr (EPI == EPI_BIAS_RESID) {
          ((float*)Cout)[idx] = f + bias[gn] + resid[idx];
        }
      }
    }
  }
}

// ---------------- merged QKV GEMM: N=2304, segment epilogue ----------------
__global__ __launch_bounds__(256) void gemm_qkv(
    const ushort* __restrict__ A, const ushort* __restrict__ Bt,
    ushort* __restrict__ qout, ushort* __restrict__ kout, ushort* __restrict__ vtout,
    int M, int K, float qscale) {
  __shared__ ushort As[128 * 64];
  __shared__ ushort Bs[128 * 64];
  const int tid = threadIdx.x;
  const int lane = tid & 63, wid = tid >> 6;
  const int wm = wid >> 1, wn = wid & 1;
  const int l15 = lane & 15, l4 = lane >> 4;
  const int m0 = blockIdx.y * 128, n0 = blockIdx.x * 128;
  const int srow = lane >> 3, sslot = lane & 7;
  const int skel = (sslot ^ srow) << 3;

  f32x4 acc[4][4] = {};

  for (int k0 = 0; k0 < K; k0 += 64) {
    __syncthreads();
#pragma unroll
    for (int i = 0; i < 4; ++i) {
      const int c = i * 4 + wid;
      const int row = c * 8 + srow;
      gload16(A + (size_t)(m0 + row) * K + k0 + skel, (char*)As + c * 1024);
      gload16(Bt + (size_t)(n0 + row) * K + k0 + skel, (char*)Bs + c * 1024);
    }
    __syncthreads();
#pragma unroll
    for (int ks = 0; ks < 2; ++ks) {
      bf16x8 af[4], bfr[4];
#pragma unroll
      for (int mi = 0; mi < 4; ++mi) {
        const int row = wm * 64 + mi * 16 + l15;
        const int slot = (ks * 4 + l4) ^ (row & 7);
        af[mi] = *(const bf16x8*)((const char*)As + row * 128 + slot * 16);
      }
#pragma unroll
      for (int ni = 0; ni < 4; ++ni) {
        const int row = wn * 64 + ni * 16 + l15;
        const int slot = (ks * 4 + l4) ^ (row & 7);
        bfr[ni] = *(const bf16x8*)((const char*)Bs + row * 128 + slot * 16);
      }
#pragma unroll
      for (int mi = 0; mi < 4; ++mi)
#pragma unroll
        for (int ni = 0; ni < 4; ++ni)
          acc[mi][ni] = MFMA16(af[mi], bfr[ni], acc[mi][ni]);
    }
  }

  const int seg = n0 / 768;  // uniform per block (768 % 128 == 0)
#pragma unroll
  for (int mi = 0; mi < 4; ++mi) {
#pragma unroll
    for (int ni = 0; ni < 4; ++ni) {
      const int gm = m0 + wm * 64 + mi * 16 + l4 * 4;
      const int gn = n0 + wn * 64 + ni * 16 + l15;
      const int col = gn - seg * 768;
      f32x4 v = acc[mi][ni];
      if (seg == 0) {
#pragma unroll
        for (int r = 0; r < 4; ++r)
          qout[(size_t)(gm + r) * 768 + col] = f2bf(v[r] * qscale);
      } else if (seg == 1) {
#pragma unroll
        for (int r = 0; r < 4; ++r)
          kout[(size_t)(gm + r) * 768 + col] = f2bf(v[r]);
      } else {
        const int b = gm >> 12, tt = gm & 4095;
        const int h = col >> 6, dh = col & 63;
        ushort4 pk;
        pk.x = f2bf(v[0]); pk.y = f2bf(v[1]); pk.z = f2bf(v[2]); pk.w = f2bf(v[3]);
        *(ushort4*)(vtout + (((size_t)(b * 12 + h) * 64 + dh) * 4096 + tt)) = pk;
      }
    }
  }
}

// ---------------- causal MFMA flash attention (8-wave key-split) --------------
// 512 threads: waves 0-3 (group A) process key range [128j,128j+64), waves 4-7
// (group B) [128j+64,128j+128) for the SAME 64 q-rows. Static max makes the
// merge additive: O = (O_A + O_B) / (d_A + d_B). XCD-chunked block swizzle.
__global__ __launch_bounds__(512, 4) void flash_attn_kernel(
    const ushort* __restrict__ Q, const ushort* __restrict__ Kb,
    const ushort* __restrict__ Vt, ushort* __restrict__ O) {
  __shared__ ushort Ks[4][64 * 64];   // [grp*2+buf][key][kd], 8-slot XOR swizzle
  __shared__ ushort Vts[4][64 * 64];  // [grp*2+buf][dh][key]
  const int tid = threadIdx.x, lane = tid & 63, wid = tid >> 6;
  const int lw = wid & 3, g = wid >> 2;
  const int l15 = lane & 15, l4 = lane >> 4, l7 = l15 & 7;
  // chunked XCD swizzle: 1536 blocks, 8 XCDs -> 192-block chunks (3 bh-columns)
  const int bid = (int)blockIdx.x;
  const int idx = (bid & 7) * 192 + (bid >> 3);
  const int bh = idx >> 6, b = bh / 12, h = bh % 12;
  const int qb = 63 - (idx & 63);  // heavy blocks first within each column
  const int qbase = qb * 64;
  const int q0 = qbase + lw * 16;

  bf16x8 qf0, qf1;
  {
    const ushort* qp = Q + ((size_t)(b * 4096 + q0 + l15) * 768 + h * 64 + l4 * 8);
    qf0 = *(const bf16x8*)qp;
    qf1 = *(const bf16x8*)(qp + 32);
  }
  f32x4 oo[4] = {};
  float dsum = 0.f;

  const int srow_l = lane >> 3;
  const int sco = ((lane & 7) ^ srow_l) << 3;  // pre-swizzled source col offset
  const ushort* Kbase = Kb + (size_t)b * 4096 * 768 + h * 64;
  const ushort* Vbase = Vt + (size_t)bh * 64 * 4096;
  const int c0 = lw, c1 = 4 + lw;
  const int gofs = g << 6;  // group's key offset within the 128-key iteration
  const ushort* kp0 = Kbase + (size_t)(gofs + c0 * 8 + srow_l) * 768 + sco;
  const ushort* kp1 = Kbase + (size_t)(gofs + c1 * 8 + srow_l) * 768 + sco;
  const ushort* vp0 = Vbase + (size_t)(c0 * 8 + srow_l) * 4096 + gofs + sco;
  const ushort* vp1 = Vbase + (size_t)(c1 * 8 + srow_l) * 4096 + gofs + sco;

  const int nt = (qb + 2) >> 1;   // 128-key iterations per block
  const int qlim = qbase + 64;    // keys < qlim are needed by this block

  const int koff0 = l15 * 128 + ((l4 ^ l7) << 4);
  const int koff1 = l15 * 128 + (((4 + l4) ^ l7) << 4);
  const int vbase_off = l15 * 128 + ((l4 & 1) << 3);
  const int t2b = l4 >> 1;

  char* KsB = (char*)Ks + g * 16384;   // this group's double buffer
  char* VtsB = (char*)Vts + g * 16384;

  // prologue: stage j=0 tile if this group needs it
  if (gofs < qlim) {
    gload16(kp0, KsB + c0 * 1024);
    gload16(kp1, KsB + c1 * 1024);
    gload16(vp0, VtsB + c0 * 1024);
    gload16(vp1, VtsB + c1 * 1024);
  }

  int cur = 0;
  for (int j = 0; j < nt; ++j) {
    const int k0w = (j << 7) + gofs;
    const bool pf = (((j + 1) << 7) + gofs) < qlim;
    if (pf) {
      kp0 += 128 * 768; kp1 += 128 * 768;
      vp0 += 128; vp1 += 128;
      const int nb = (cur ^ 1) * 8192;
      gload16(kp0, KsB + nb + c0 * 1024);
      gload16(kp1, KsB + nb + c1 * 1024);
      gload16(vp0, VtsB + nb + c0 * 1024);
      gload16(vp1, VtsB + nb + c1 * 1024);
      asm volatile("s_waitcnt vmcnt(4)" ::: "memory");
    } else {
      asm volatile("s_waitcnt vmcnt(0)" ::: "memory");
    }
    __builtin_amdgcn_s_barrier();

    const int nf = (q0 + 16 - k0w) >> 4;
    const int nct = nf < 0 ? 0 : (nf < 4 ? nf : 4);
    const bool has_diag = (nf <= 4);
    const char* Kc = KsB + cur * 8192;
    const char* Vc = VtsB + cur * 8192;

    __builtin_amdgcn_s_setprio(1);
#pragma unroll
    for (int ct = 0; ct < 4; ++ct) {
      if (ct < nct) {
        // S^T = mfma(K, Q): lane holds key=ct*16+l4*4+r, qrow=l15
        f32x4 s = {0.f, 0.f, 0.f, 0.f};
        const bf16x8 kf0 = *(const bf16x8*)(Kc + ct * 2048 + koff0);
        const bf16x8 kf1 = *(const bf16x8*)(Kc + ct * 2048 + koff1);
        s = MFMA16(kf0, qf0, s);
        s = MFMA16(kf1, qf1, s);
        if (has_diag && ct == nct - 1) {
#pragma unroll
          for (int r = 0; r < 4; ++r)
            if (l4 * 4 + r > l15) s[r] = -30.f;  // exp2(-30) ~ 1e-9
        }
        const float p0 = __builtin_amdgcn_exp2f(s[0]);
        const float p1 = __builtin_amdgcn_exp2f(s[1]);
        const float p2 = __builtin_amdgcn_exp2f(s[2]);
        const float p3 = __builtin_amdgcn_exp2f(s[3]);
        dsum += (p0 + p1) + (p2 + p3);
        union { bf16x4 v; ushort u[4]; } pk;
        pk.u[0] = f2bf(p0); pk.u[1] = f2bf(p1);
        pk.u[2] = f2bf(p2); pk.u[3] = f2bf(p3);
        const int xo = ((2 * ct + t2b) ^ l7) << 4;
#pragma unroll
        for (int dt = 0; dt < 4; ++dt) {
          const bf16x4 vf = *(const bf16x4*)(Vc + dt * 2048 + vbase_off + xo);
          oo[dt] = mfma_k16(pk.v, vf, oo[dt]);
        }
      }
    }
    __builtin_amdgcn_s_setprio(0);
    asm volatile("" ::: "memory");
    __builtin_amdgcn_s_barrier();
    cur ^= 1;
  }

  // ---- combine group partials (additive: static max, no rescale) ----
  __syncthreads();  // full drain before reusing Ks as scratch
  float* sm = (float*)Ks;  // 32KB scratch, need 17.4KB
  if (g == 1) {
    const int base = (lw * 64 + lane) * 17;  // stride 17: conflict-free
#pragma unroll
    for (int dt = 0; dt < 4; ++dt)
#pragma unroll
      for (int r = 0; r < 4; ++r) sm[base + dt * 4 + r] = oo[dt][r];
    sm[base + 16] = dsum;
  }
  __syncthreads();
  if (g == 0) {
    const int base = (lw * 64 + lane) * 17;
#pragma unroll
    for (int dt = 0; dt < 4; ++dt)
#pragma unroll
      for (int r = 0; r < 4; ++r) oo[dt][r] += sm[base + dt * 4 + r];
    dsum += sm[base + 16];
    dsum += __shfl_xor(dsum, 16);
    dsum += __shfl_xor(dsum, 32);  // all l4-copies hold denom(q0+l15)
    ushort* op = O + ((size_t)(b * 4096 + q0 + l4 * 4) * 768 + h * 64);
#pragma unroll
    for (int r = 0; r < 4; ++r) {
      const float inv = 1.0f / __shfl(dsum, l4 * 4 + r);
#pragma unroll
      for (int dt = 0; dt < 4; ++dt)
        op[(size_t)r * 768 + dt * 16 + l15] = f2bf(oo[dt][r] * inv);
    }
  }
}

extern "C" void kernel_launch(void* const* d_in, const int* in_sizes, int n_in,
                              void* d_out, int out_size, void* d_ws, size_t ws_size,
                              hipStream_t stream) {
  const float* x  = (const float*)d_in[0];
  const float* wq = (const float*)d_in[1];
  const float* wk = (const float*)d_in[2];
  const float* wv = (const float*)d_in[3];
  const float* wo = (const float*)d_in[4];
  const float* w1 = (const float*)d_in[5];
  const float* b1 = (const float*)d_in[6];
  const float* w2 = (const float*)d_in[7];
  const float* b2 = (const float*)d_in[8];
  const float* g1 = (const float*)d_in[9];
  const float* g2 = (const float*)d_in[10];
  float* out = (float*)d_out;

  char* p = (char*)d_ws;
  ushort* wqT = (ushort*)p; p += (size_t)768 * 768 * 2;   // } contiguous: acts as
  ushort* wkT = (ushort*)p; p += (size_t)768 * 768 * 2;   // } one 2304x768 B matrix
  ushort* wvT = (ushort*)p; p += (size_t)768 * 768 * 2;   // } for merged QKV GEMM
  ushort* woT = (ushort*)p; p += (size_t)768 * 768 * 2;
  ushort* w1T = (ushort*)p; p += (size_t)3072 * 768 * 2;
  ushort* w2T = (ushort*)p; p += (size_t)768 * 3072 * 2;
  ushort* xn  = (ushort*)p; p += (size_t)8192 * 768 * 2;
  ushort* qb  = (ushort*)p; p += (size_t)8192 * 768 * 2;
  ushort* kb  = (ushort*)p; p += (size_t)8192 * 768 * 2;
  ushort* vtb = (ushort*)p; p += (size_t)8192 * 768 * 2;
  ushort* attn = (ushort*)p; p += (size_t)8192 * 768 * 2;
  float* x2 = (float*)p; p += (size_t)8192 * 768 * 4;
  ushort* hf = qb;  // reuse qb..attn region (exactly 8192*3072*2 bytes)

  // Q pre-scale folds 1/sqrt(64) and 1/ln2 (softmax computed in exp2 units)
  const float qscale = 0.125f * 1.44269504088896340736f;

  dim3 blk(256);
  wtrans_all<<<dim3(6912), blk, 0, stream>>>(wq, wk, wv, wo, w1, w2,
                                             wqT, wkT, wvT, woT, w1T, w2T);

  rmsnorm_kernel<<<8192, blk, 0, stream>>>(x, g1, xn);

  gemm_qkv<<<dim3(18, 64), blk, 0, stream>>>(xn, wqT, qb, kb, vtb, 8192, 768, qscale);

  flash_attn_kernel<<<dim3(1536), dim3(512), 0, stream>>>(qb, kb, vtb, attn);

  gemm_bt<EPI_RESID><<<dim3(6, 64), blk, 0, stream>>>(attn, woT, x2, nullptr, x, 8192, 768, 768, 1.0f);

  rmsnorm_kernel<<<8192, blk, 0, stream>>>(x2, g2, xn);

  gemm_bt<EPI_BIAS_GELU><<<dim3(24, 64), blk, 0, stream>>>(xn, w1T, hf, b1, nullptr, 8192, 3072, 768, 1.0f);
  gemm_bt<EPI_BIAS_RESID><<<dim3(6, 64), blk, 0, stream>>>(hf, w2T, out, b2, x2, 8192, 768, 3072, 1.0f);
}

// Round 9
// 326.930 us; speedup vs baseline: 1.7634x; 1.0480x over previous
//
#include <hip/hip_runtime.h>
#include <hip/hip_bf16.h>

typedef __attribute__((ext_vector_type(8))) short bf16x8;
typedef __attribute__((ext_vector_type(4))) short bf16x4;
typedef __attribute__((ext_vector_type(4))) float f32x4;

#define MFMA16(a, b, c) __builtin_amdgcn_mfma_f32_16x16x32_bf16((a), (b), (c), 0, 0, 0)

__device__ __forceinline__ f32x4 mfma_k16(bf16x4 a, bf16x4 b, f32x4 c) {
#if __has_builtin(__builtin_amdgcn_mfma_f32_16x16x16bf16_1k)
  return __builtin_amdgcn_mfma_f32_16x16x16bf16_1k(a, b, c, 0, 0, 0);
#elif __has_builtin(__builtin_amdgcn_mfma_f32_16x16x16_bf16)
  return __builtin_amdgcn_mfma_f32_16x16x16_bf16(a, b, c, 0, 0, 0);
#else
  asm("v_mfma_f32_16x16x16_bf16 %0, %1, %2, %0" : "+v"(c) : "v"(a), "v"(b));
  return c;
#endif
}

__device__ __forceinline__ ushort f2bf(float f) {
  union { __hip_bfloat16 h; ushort u; } cv;
  cv.h = __float2bfloat16(f);
  return cv.u;
}

__device__ __forceinline__ void gload16(const void* g, void* l) {
  __builtin_amdgcn_global_load_lds((const __attribute__((address_space(1))) void*)g,
                                   (__attribute__((address_space(3))) void*)l, 16, 0, 0);
}

// ---------------- merged weight transpose+cast: all 6 matrices ----------------
__global__ void wtrans_all(const float* __restrict__ wq, const float* __restrict__ wk,
                           const float* __restrict__ wv, const float* __restrict__ wo,
                           const float* __restrict__ w1, const float* __restrict__ w2,
                           ushort* __restrict__ wqT, ushort* __restrict__ wkT,
                           ushort* __restrict__ wvT, ushort* __restrict__ woT,
                           ushort* __restrict__ w1T, ushort* __restrict__ w2T) {
  __shared__ float t[32][33];
  int id = blockIdx.x;
  const float* W;
  ushort* Wt;
  int K, N, nbx;
  if (id < 2304) {  // 4 square 768x768 matrices, 576 tiles each
    const int m = id / 576;
    id -= m * 576;
    W = (m == 0) ? wq : (m == 1) ? wk : (m == 2) ? wv : wo;
    Wt = (m == 0) ? wqT : (m == 1) ? wkT : (m == 2) ? wvT : woT;
    K = 768; N = 768; nbx = 24;
  } else if (id < 4608) {
    id -= 2304; W = w1; Wt = w1T; K = 768; N = 3072; nbx = 96;
  } else {
    id -= 4608; W = w2; Wt = w2T; K = 3072; N = 768; nbx = 24;
  }
  const int nb = (id % nbx) * 32, kb = (id / nbx) * 32;
  const int tx = threadIdx.x & 31, ty = threadIdx.x >> 5;
#pragma unroll
  for (int i = 0; i < 4; ++i)
    t[ty + i * 8][tx] = W[(size_t)(kb + ty + i * 8) * N + nb + tx];
  __syncthreads();
#pragma unroll
  for (int i = 0; i < 4; ++i)
    Wt[(size_t)(nb + ty + i * 8) * K + kb + tx] = f2bf(t[tx][ty + i * 8]);
}

// ---------------- RMSNorm fp32 row(768) -> bf16 ----------------
__global__ void rmsnorm_kernel(const float* __restrict__ x, const float* __restrict__ g,
                               ushort* __restrict__ out) {
  const int row = blockIdx.x;
  const float* xr = x + (size_t)row * 768;
  const int t = threadIdx.x;
  float v0 = xr[t], v1 = xr[t + 256], v2 = xr[t + 512];
  float ss = v0 * v0 + v1 * v1 + v2 * v2;
#pragma unroll
  for (int off = 1; off < 64; off <<= 1) ss += __shfl_xor(ss, off);
  __shared__ float part[4];
  if ((t & 63) == 0) part[t >> 6] = ss;
  __syncthreads();
  const float tot = part[0] + part[1] + part[2] + part[3];
  const float r = rsqrtf(tot * (1.0f / 768.0f) + 1e-6f);
  ushort* orow = out + (size_t)row * 768;
  orow[t]       = f2bf(v0 * r * g[t]);
  orow[t + 256] = f2bf(v1 * r * g[t + 256]);
  orow[t + 512] = f2bf(v2 * r * g[t + 512]);
}

// ------ GEMM: C(MxN) = A(MxK,bf16)*Bt(NxK,bf16)^T, 2-phase counted vmcnt ------
enum { EPI_BF16 = 0, EPI_VT = 1, EPI_RESID = 2, EPI_BIAS_GELU = 3, EPI_BIAS_RESID = 4 };

template <int EPI>
__global__ __launch_bounds__(256) void gemm_bt(
    const ushort* __restrict__ A, const ushort* __restrict__ Bt, void* __restrict__ Cout,
    const float* __restrict__ bias, const float* __restrict__ resid, int M, int N, int K,
    float scale) {
  __shared__ ushort As[2][128 * 64];
  __shared__ ushort Bs[2][128 * 64];
  const int tid = threadIdx.x;
  const int lane = tid & 63, wid = tid >> 6;
  const int wm = wid >> 1, wn = wid & 1;
  const int l15 = lane & 15, l4 = lane >> 4;
  const int m0 = blockIdx.y * 128, n0 = blockIdx.x * 128;
  const int srow = lane >> 3, sslot = lane & 7;
  const int skel = (sslot ^ srow) << 3;  // pre-swizzled source k offset

  f32x4 acc[4][4] = {};

  // prologue: stage k-tile 0 into buffer 0
#pragma unroll
  for (int i = 0; i < 4; ++i) {
    const int c = i * 4 + wid;
    const int row = c * 8 + srow;
    gload16(A + (size_t)(m0 + row) * K + skel, (char*)As[0] + c * 1024);
    gload16(Bt + (size_t)(n0 + row) * K + skel, (char*)Bs[0] + c * 1024);
  }

  int cur = 0;
  for (int k0 = 0; k0 < K; k0 += 64) {
    if (k0 + 64 < K) {
      char* dA = (char*)As[cur ^ 1];
      char* dB = (char*)Bs[cur ^ 1];
#pragma unroll
      for (int i = 0; i < 4; ++i) {
        const int c = i * 4 + wid;
        const int row = c * 8 + srow;
        gload16(A + (size_t)(m0 + row) * K + k0 + 64 + skel, dA + c * 1024);
        gload16(Bt + (size_t)(n0 + row) * K + k0 + 64 + skel, dB + c * 1024);
      }
      asm volatile("s_waitcnt vmcnt(8)" ::: "memory");  // current tile landed
    } else {
      asm volatile("s_waitcnt vmcnt(0)" ::: "memory");
    }
    __builtin_amdgcn_s_barrier();

    const char* pA = (const char*)As[cur];
    const char* pB = (const char*)Bs[cur];
#pragma unroll
    for (int ks = 0; ks < 2; ++ks) {
      bf16x8 af[4], bfr[4];
#pragma unroll
      for (int mi = 0; mi < 4; ++mi) {
        const int row = wm * 64 + mi * 16 + l15;
        const int slot = (ks * 4 + l4) ^ (row & 7);
        af[mi] = *(const bf16x8*)(pA + row * 128 + slot * 16);
      }
#pragma unroll
      for (int ni = 0; ni < 4; ++ni) {
        const int row = wn * 64 + ni * 16 + l15;
        const int slot = (ks * 4 + l4) ^ (row & 7);
        bfr[ni] = *(const bf16x8*)(pB + row * 128 + slot * 16);
      }
#pragma unroll
      for (int mi = 0; mi < 4; ++mi)
#pragma unroll
        for (int ni = 0; ni < 4; ++ni)
          acc[mi][ni] = MFMA16(af[mi], bfr[ni], acc[mi][ni]);
    }
    asm volatile("" ::: "memory");
    __builtin_amdgcn_s_barrier();  // all waves done reading buf[cur]
    cur ^= 1;
  }

#pragma unroll
  for (int mi = 0; mi < 4; ++mi) {
#pragma unroll
    for (int ni = 0; ni < 4; ++ni) {
      const int gm = m0 + wm * 64 + mi * 16 + l4 * 4;
      const int gn = n0 + wn * 64 + ni * 16 + l15;
      f32x4 v = acc[mi][ni];
#pragma unroll
      for (int r = 0; r < 4; ++r) {
        const size_t idx = (size_t)(gm + r) * N + gn;
        const float f = v[r];
        if constexpr (EPI == EPI_BF16) {
          ((ushort*)Cout)[idx] = f2bf(f * scale);
        } else if constexpr (EPI == EPI_RESID) {
          ((float*)Cout)[idx] = f + resid[idx];
        } else if constexpr (EPI == EPI_BIAS_GELU) {
          const float u = f + bias[gn];
          const float gl = 0.5f * u * (1.0f + erff(u * 0.70710678118654752f));
          ((ushort*)Cout)[idx] = f2bf(gl);
        } else if constexpr (EPI == EPI_BIAS_RESID) {
          ((float*)Cout)[idx] = f + bias[gn] + resid[idx];
        }
      }
    }
  }
}

// ------------- merged QKV GEMM: N=2304, segment epilogue, 2-phase -------------
__global__ __launch_bounds__(256) void gemm_qkv(
    const ushort* __restrict__ A, const ushort* __restrict__ Bt,
    ushort* __restrict__ qout, ushort* __restrict__ kout, ushort* __restrict__ vtout,
    int M, int K, float qscale) {
  __shared__ ushort As[2][128 * 64];
  __shared__ ushort Bs[2][128 * 64];
  const int tid = threadIdx.x;
  const int lane = tid & 63, wid = tid >> 6;
  const int wm = wid >> 1, wn = wid & 1;
  const int l15 = lane & 15, l4 = lane >> 4;
  const int m0 = blockIdx.y * 128, n0 = blockIdx.x * 128;
  const int srow = lane >> 3, sslot = lane & 7;
  const int skel = (sslot ^ srow) << 3;

  f32x4 acc[4][4] = {};

#pragma unroll
  for (int i = 0; i < 4; ++i) {
    const int c = i * 4 + wid;
    const int row = c * 8 + srow;
    gload16(A + (size_t)(m0 + row) * K + skel, (char*)As[0] + c * 1024);
    gload16(Bt + (size_t)(n0 + row) * K + skel, (char*)Bs[0] + c * 1024);
  }

  int cur = 0;
  for (int k0 = 0; k0 < K; k0 += 64) {
    if (k0 + 64 < K) {
      char* dA = (char*)As[cur ^ 1];
      char* dB = (char*)Bs[cur ^ 1];
#pragma unroll
      for (int i = 0; i < 4; ++i) {
        const int c = i * 4 + wid;
        const int row = c * 8 + srow;
        gload16(A + (size_t)(m0 + row) * K + k0 + 64 + skel, dA + c * 1024);
        gload16(Bt + (size_t)(n0 + row) * K + k0 + 64 + skel, dB + c * 1024);
      }
      asm volatile("s_waitcnt vmcnt(8)" ::: "memory");
    } else {
      asm volatile("s_waitcnt vmcnt(0)" ::: "memory");
    }
    __builtin_amdgcn_s_barrier();

    const char* pA = (const char*)As[cur];
    const char* pB = (const char*)Bs[cur];
#pragma unroll
    for (int ks = 0; ks < 2; ++ks) {
      bf16x8 af[4], bfr[4];
#pragma unroll
      for (int mi = 0; mi < 4; ++mi) {
        const int row = wm * 64 + mi * 16 + l15;
        const int slot = (ks * 4 + l4) ^ (row & 7);
        af[mi] = *(const bf16x8*)(pA + row * 128 + slot * 16);
      }
#pragma unroll
      for (int ni = 0; ni < 4; ++ni) {
        const int row = wn * 64 + ni * 16 + l15;
        const int slot = (ks * 4 + l4) ^ (row & 7);
        bfr[ni] = *(const bf16x8*)(pB + row * 128 + slot * 16);
      }
#pragma unroll
      for (int mi = 0; mi < 4; ++mi)
#pragma unroll
        for (int ni = 0; ni < 4; ++ni)
          acc[mi][ni] = MFMA16(af[mi], bfr[ni], acc[mi][ni]);
    }
    asm volatile("" ::: "memory");
    __builtin_amdgcn_s_barrier();
    cur ^= 1;
  }

  const int seg = n0 / 768;  // uniform per block (768 % 128 == 0)
#pragma unroll
  for (int mi = 0; mi < 4; ++mi) {
#pragma unroll
    for (int ni = 0; ni < 4; ++ni) {
      const int gm = m0 + wm * 64 + mi * 16 + l4 * 4;
      const int gn = n0 + wn * 64 + ni * 16 + l15;
      const int col = gn - seg * 768;
      f32x4 v = acc[mi][ni];
      if (seg == 0) {
#pragma unroll
        for (int r = 0; r < 4; ++r)
          qout[(size_t)(gm + r) * 768 + col] = f2bf(v[r] * qscale);
      } else if (seg == 1) {
#pragma unroll
        for (int r = 0; r < 4; ++r)
          kout[(size_t)(gm + r) * 768 + col] = f2bf(v[r]);
      } else {
        const int b = gm >> 12, tt = gm & 4095;
        const int h = col >> 6, dh = col & 63;
        ushort4 pk;
        pk.x = f2bf(v[0]); pk.y = f2bf(v[1]); pk.z = f2bf(v[2]); pk.w = f2bf(v[3]);
        *(ushort4*)(vtout + (((size_t)(b * 12 + h) * 64 + dh) * 4096 + tt)) = pk;
      }
    }
  }
}

// ---------------- causal MFMA flash attention (KVBLK=64, XCD-clustered) ------
// Q,K row-major [B*T][768] bf16 (Q pre-scaled by 0.125/ln2); Vt [B][H][64][T].
// 16 q-rows/wave, 64 q/block, 1536 blocks. Chunked XCD swizzle: each XCD owns
// 3 whole (b,h) columns -> K/V working set 3MB fits its 4MB L2. Swapped QK^T,
// static max, deferred denominator, double-buffered, counted vmcnt, setprio.
__global__ __launch_bounds__(256, 5) void flash_attn_kernel(
    const ushort* __restrict__ Q, const ushort* __restrict__ Kb,
    const ushort* __restrict__ Vt, ushort* __restrict__ O) {
  __shared__ ushort Ks[2][64 * 64];   // [key][kd], 8-slot XOR swizzle
  __shared__ ushort Vts[2][64 * 64];  // [dh][key], 8-slot XOR swizzle
  const int tid = threadIdx.x, lane = tid & 63, wid = tid >> 6;
  const int l15 = lane & 15, l4 = lane >> 4;
  const int l7 = l15 & 7;
  // chunked XCD swizzle: 1536 blocks, 8 XCDs -> 192-block chunks (3 bh-columns)
  const int bid = (int)blockIdx.x;
  const int idx = (bid & 7) * 192 + (bid >> 3);
  const int bh = idx >> 6, b = bh / 12, h = bh % 12;
  const int qb = 63 - (idx & 63);  // heavy blocks first within each column
  const int qbase = qb * 64;
  const int q0 = qbase + wid * 16;

  bf16x8 qf0, qf1;
  {
    const ushort* qp = Q + ((size_t)(b * 4096 + q0 + l15) * 768 + h * 64 + l4 * 8);
    qf0 = *(const bf16x8*)qp;
    qf1 = *(const bf16x8*)(qp + 32);
  }
  f32x4 oo[4] = {};
  float dsum = 0.f;  // per-lane partial denominator for qrow = q0 + l15

  // staging: persistent per-lane pointers, advanced by uniform strides
  const int srow_l = lane >> 3;                // row within 8-row group
  const int sco = ((lane & 7) ^ srow_l) << 3;  // swizzled source col offset (elems)
  const ushort* Kbase = Kb + (size_t)b * 4096 * 768 + h * 64;
  const ushort* Vbase = Vt + (size_t)bh * 64 * 4096;
  const int c0 = wid, c1 = 4 + wid;  // this wave's two 8-row chunks
  const ushort* kp0 = Kbase + (size_t)(c0 * 8 + srow_l) * 768 + sco;
  const ushort* kp1 = Kbase + (size_t)(c1 * 8 + srow_l) * 768 + sco;
  const ushort* vp0 = Vbase + (size_t)(c0 * 8 + srow_l) * 4096 + sco;
  const ushort* vp1 = Vbase + (size_t)(c1 * 8 + srow_l) * 4096 + sco;
  const int nt = qb + 1;

  // ct-invariant LDS read offsets (dt*16 and ct*16 are 0 mod 8)
  const int koff0 = l15 * 128 + ((l4 ^ l7) << 4);        // K frag, ks=0
  const int koff1 = l15 * 128 + (((4 + l4) ^ l7) << 4);  // K frag, ks=1
  const int vbase_off = l15 * 128 + ((l4 & 1) << 3);     // V frag base
  const int t2b = l4 >> 1;

  // ---- prologue: stage tile 0 into buffer 0 ----
  gload16(kp0, (char*)Ks + c0 * 1024);
  gload16(kp1, (char*)Ks + c1 * 1024);
  gload16(vp0, (char*)Vts + c0 * 1024);
  gload16(vp1, (char*)Vts + c1 * 1024);

  int cur = 0;
  for (int kt = 0; kt < nt; ++kt) {
    const int k0 = kt << 6;
    if (kt + 1 < nt) {
      kp0 += 64 * 768; kp1 += 64 * 768;  // next 64 keys
      vp0 += 64; vp1 += 64;              // next 64 t-columns
      const int nb = (cur ^ 1) * 8192;
      gload16(kp0, (char*)Ks + nb + c0 * 1024);
      gload16(kp1, (char*)Ks + nb + c1 * 1024);
      gload16(vp0, (char*)Vts + nb + c0 * 1024);
      gload16(vp1, (char*)Vts + nb + c1 * 1024);
      asm volatile("s_waitcnt vmcnt(4)" ::: "memory");  // current tile's loads done
    } else {
      asm volatile("s_waitcnt vmcnt(0)" ::: "memory");
    }
    __builtin_amdgcn_s_barrier();

    const int nf = (q0 + 16 - k0) >> 4;  // >= 1 always
    const int nct = nf < 4 ? nf : 4;
    const bool has_diag = (nf <= 4);
    const char* Kc = (const char*)Ks + cur * 8192;
    const char* Vc = (const char*)Vts + cur * 8192;

    __builtin_amdgcn_s_setprio(1);
#pragma unroll
    for (int ct = 0; ct < 4; ++ct) {
      if (ct < nct) {
        // ---- S^T = mfma(K, Q): lane holds key=ct*16+l4*4+r, qrow=l15 ----
        f32x4 s = {0.f, 0.f, 0.f, 0.f};
        const bf16x8 kf0 = *(const bf16x8*)(Kc + ct * 2048 + koff0);
        const bf16x8 kf1 = *(const bf16x8*)(Kc + ct * 2048 + koff1);
        s = MFMA16(kf0, qf0, s);
        s = MFMA16(kf1, qf1, s);
        if (has_diag && ct == nct - 1) {
#pragma unroll
          for (int r = 0; r < 4; ++r)
            if (l4 * 4 + r > l15) s[r] = -30.f;  // exp2(-30) ~ 1e-9
        }
        // ---- exp2 + deferred denom + pack ----
        const float p0 = __builtin_amdgcn_exp2f(s[0]);
        const float p1 = __builtin_amdgcn_exp2f(s[1]);
        const float p2 = __builtin_amdgcn_exp2f(s[2]);
        const float p3 = __builtin_amdgcn_exp2f(s[3]);
        dsum += (p0 + p1) + (p2 + p3);
        union { bf16x4 v; ushort u[4]; } pk;
        pk.u[0] = f2bf(p0); pk.u[1] = f2bf(p1);
        pk.u[2] = f2bf(p2); pk.u[3] = f2bf(p3);
        // ---- PV: P stays in registers; V frag = 4 consecutive keys ----
        const int xo = ((2 * ct + t2b) ^ l7) << 4;
#pragma unroll
        for (int dt = 0; dt < 4; ++dt) {
          const bf16x4 vf = *(const bf16x4*)(Vc + dt * 2048 + vbase_off + xo);
          oo[dt] = mfma_k16(pk.v, vf, oo[dt]);
        }
      }
    }
    __builtin_amdgcn_s_setprio(0);
    asm volatile("" ::: "memory");
    __builtin_amdgcn_s_barrier();
    cur ^= 1;
  }

  // ---- final denominator reduce + normalize + store ----
  dsum += __shfl_xor(dsum, 16);
  dsum += __shfl_xor(dsum, 32);  // all l4-copies now hold full denom(q0+l15)
  ushort* op = O + ((size_t)(b * 4096 + q0 + l4 * 4) * 768 + h * 64);
#pragma unroll
  for (int r = 0; r < 4; ++r) {
    const float inv = 1.0f / __shfl(dsum, l4 * 4 + r);
#pragma unroll
    for (int dt = 0; dt < 4; ++dt)
      op[(size_t)r * 768 + dt * 16 + l15] = f2bf(oo[dt][r] * inv);
  }
}

extern "C" void kernel_launch(void* const* d_in, const int* in_sizes, int n_in,
                              void* d_out, int out_size, void* d_ws, size_t ws_size,
                              hipStream_t stream) {
  const float* x  = (const float*)d_in[0];
  const float* wq = (const float*)d_in[1];
  const float* wk = (const float*)d_in[2];
  const float* wv = (const float*)d_in[3];
  const float* wo = (const float*)d_in[4];
  const float* w1 = (const float*)d_in[5];
  const float* b1 = (const float*)d_in[6];
  const float* w2 = (const float*)d_in[7];
  const float* b2 = (const float*)d_in[8];
  const float* g1 = (const float*)d_in[9];
  const float* g2 = (const float*)d_in[10];
  float* out = (float*)d_out;

  char* p = (char*)d_ws;
  ushort* wqT = (ushort*)p; p += (size_t)768 * 768 * 2;   // } contiguous: acts as
  ushort* wkT = (ushort*)p; p += (size_t)768 * 768 * 2;   // } one 2304x768 B matrix
  ushort* wvT = (ushort*)p; p += (size_t)768 * 768 * 2;   // } for merged QKV GEMM
  ushort* woT = (ushort*)p; p += (size_t)768 * 768 * 2;
  ushort* w1T = (ushort*)p; p += (size_t)3072 * 768 * 2;
  ushort* w2T = (ushort*)p; p += (size_t)768 * 3072 * 2;
  ushort* xn  = (ushort*)p; p += (size_t)8192 * 768 * 2;
  ushort* qb  = (ushort*)p; p += (size_t)8192 * 768 * 2;
  ushort* kb  = (ushort*)p; p += (size_t)8192 * 768 * 2;
  ushort* vtb = (ushort*)p; p += (size_t)8192 * 768 * 2;
  ushort* attn = (ushort*)p; p += (size_t)8192 * 768 * 2;
  float* x2 = (float*)p; p += (size_t)8192 * 768 * 4;
  ushort* hf = qb;  // reuse qb..attn region (exactly 8192*3072*2 bytes)

  // Q pre-scale folds 1/sqrt(64) and 1/ln2 (softmax computed in exp2 units)
  const float qscale = 0.125f * 1.44269504088896340736f;

  dim3 blk(256);
  wtrans_all<<<dim3(6912), blk, 0, stream>>>(wq, wk, wv, wo, w1, w2,
                                             wqT, wkT, wvT, woT, w1T, w2T);

  rmsnorm_kernel<<<8192, blk, 0, stream>>>(x, g1, xn);

  gemm_qkv<<<dim3(18, 64), blk, 0, stream>>>(xn, wqT, qb, kb, vtb, 8192, 768, qscale);

  flash_attn_kernel<<<dim3(1536), blk, 0, stream>>>(qb, kb, vtb, attn);

  gemm_bt<EPI_RESID><<<dim3(6, 64), blk, 0, stream>>>(attn, woT, x2, nullptr, x, 8192, 768, 768, 1.0f);

  rmsnorm_kernel<<<8192, blk, 0, stream>>>(x2, g2, xn);

  gemm_bt<EPI_BIAS_GELU><<<dim3(24, 64), blk, 0, stream>>>(xn, w1T, hf, b1, nullptr, 8192, 3072, 768, 1.0f);
  gemm_bt<EPI_BIAS_RESID><<<dim3(6, 64), blk, 0, stream>>>(hf, w2T, out, b2, x2, 8192, 768, 3072, 1.0f);
}